// Round 1
// baseline (15983.807 us; speedup 1.0000x reference)
//
#include <hip/hip_runtime.h>
#include <math.h>

#define NHEADS   8
#define DHEAD    64
#define DIMM     512
#define MLPD     2048
#define NPATCH   1024
#define NTOK     1025
#define BATCH    4
#define ROWS     (BATCH*NTOK)   /* 4100 */
#define ATT_SCALE 0.125f
#define LN_EPS   1e-5f

__device__ __forceinline__ float wsum(float v) {
#pragma unroll
  for (int o = 32; o > 0; o >>= 1) v += __shfl_xor(v, o, 64);
  return v;
}
__device__ __forceinline__ float wmax(float v) {
#pragma unroll
  for (int o = 32; o > 0; o >>= 1) v = fmaxf(v, __shfl_xor(v, o, 64));
  return v;
}

// ---------------------------------------------------------------------------
// Generic fp32 GEMM: C[M,N] = A[M,K] @ B[K,N] (+bias) (+gelu) (+residual)
// 64x64 tile, BK=16, 256 threads, 4x4 micro-tile per thread.
// N and K must be multiples of 64/16 (true for all calls); M bound-checked.
// act: 0 = none, 1 = exact gelu (applied after bias, before residual).
// ---------------------------------------------------------------------------
__global__ __launch_bounds__(256) void gemm_k(
    const float* __restrict__ A, const float* __restrict__ B,
    const float* __restrict__ bias, const float* __restrict__ res,
    float* __restrict__ C, int M, int N, int K, int act)
{
  __shared__ float sA[16][65];
  __shared__ float sB[16][64];
  const int tid = threadIdx.x;
  const int m0 = blockIdx.y * 64, n0 = blockIdx.x * 64;
  const int ar = tid >> 2, ak = (tid & 3) << 2;   // A tile load: row, k4
  const int bk = tid >> 4, bn = (tid & 15) << 2;  // B tile load: k, col4
  const int ty = tid >> 4, tx = tid & 15;         // compute mapping

  float acc[4][4] = {};

  for (int k0 = 0; k0 < K; k0 += 16) {
    float4 av = make_float4(0.f, 0.f, 0.f, 0.f);
    if (m0 + ar < M)
      av = *(const float4*)(A + (size_t)(m0 + ar) * K + k0 + ak);
    float4 bv = *(const float4*)(B + (size_t)(k0 + bk) * N + n0 + bn);
    __syncthreads();
    sA[ak + 0][ar] = av.x; sA[ak + 1][ar] = av.y;
    sA[ak + 2][ar] = av.z; sA[ak + 3][ar] = av.w;
    *(float4*)&sB[bk][bn] = bv;
    __syncthreads();
#pragma unroll
    for (int kk = 0; kk < 16; kk++) {
      float a[4], b[4];
#pragma unroll
      for (int i = 0; i < 4; i++) a[i] = sA[kk][ty * 4 + i];
      float4 b4 = *(const float4*)&sB[kk][tx * 4];
      b[0] = b4.x; b[1] = b4.y; b[2] = b4.z; b[3] = b4.w;
#pragma unroll
      for (int i = 0; i < 4; i++)
#pragma unroll
        for (int j = 0; j < 4; j++)
          acc[i][j] = fmaf(a[i], b[j], acc[i][j]);
    }
  }

#pragma unroll
  for (int i = 0; i < 4; i++) {
    int row = m0 + ty * 4 + i;
    if (row >= M) continue;
#pragma unroll
    for (int j = 0; j < 4; j++) {
      int col = n0 + tx * 4 + j;
      float v = acc[i][j];
      if (bias) v += bias[col];
      if (act == 1) v = 0.5f * v * (1.0f + erff(v * 0.70710678118654752f));
      if (res) v += res[(size_t)row * N + col];
      C[(size_t)row * N + col] = v;
    }
  }
}

// ---------------------------------------------------------------------------
// LayerNorm over last dim (512): one wave per row, 4 rows per block.
// ---------------------------------------------------------------------------
__global__ __launch_bounds__(256) void ln_k(
    const float* __restrict__ X, const float* __restrict__ s,
    const float* __restrict__ b, float* __restrict__ Y, int nrows)
{
  const int w = threadIdx.x >> 6, lane = threadIdx.x & 63;
  const int row = blockIdx.x * 4 + w;
  if (row >= nrows) return;
  const float* x = X + (size_t)row * DIMM;
  float4 v0 = *(const float4*)(x + lane * 8);
  float4 v1 = *(const float4*)(x + lane * 8 + 4);
  float xv[8] = {v0.x, v0.y, v0.z, v0.w, v1.x, v1.y, v1.z, v1.w};
  float sum = 0.f, sq = 0.f;
#pragma unroll
  for (int i = 0; i < 8; i++) { sum += xv[i]; sq += xv[i] * xv[i]; }
  sum = wsum(sum); sq = wsum(sq);
  const float mean = sum * (1.0f / DIMM);
  const float var  = sq * (1.0f / DIMM) - mean * mean;
  const float r    = rsqrtf(var + LN_EPS);
  float* y = Y + (size_t)row * DIMM;
#pragma unroll
  for (int i = 0; i < 8; i++) {
    int d = lane * 8 + i;
    y[d] = (xv[i] - mean) * r * s[d] + b[d];
  }
}

// ---------------------------------------------------------------------------
// Assemble x = concat(cls, patch_embed) + pos_emb
// ---------------------------------------------------------------------------
__global__ __launch_bounds__(256) void assemble_k(
    const float* __restrict__ emb, const float* __restrict__ cls,
    const float* __restrict__ pos, float* __restrict__ X)
{
  int idx = blockIdx.x * 256 + threadIdx.x;
  if (idx >= BATCH * NTOK * DIMM) return;
  int d = idx & (DIMM - 1);
  int t = (idx >> 9) % NTOK;
  int b = idx / (NTOK * DIMM);
  float v = (t == 0) ? cls[d] : emb[((size_t)b * NPATCH + (t - 1)) * DIMM + d];
  X[idx] = v + pos[(size_t)t * DIMM + d];
}

// ---------------------------------------------------------------------------
// Flash-style attention. qkv layout: [B, NTOK, 1536] with q|k|v each 512 cols,
// head h in cols h*64..h*64+63. Grid: (ceil(NTOK/16), B*NHEADS), 256 threads.
// Wave w handles q rows tile*16 + w*4 + {0..3}; lane owns output dim = lane.
// ---------------------------------------------------------------------------
__global__ __launch_bounds__(256) void attn_k(
    const float* __restrict__ qkv, float* __restrict__ out)
{
  __shared__ float ks[64][65];
  __shared__ float vs[64][65];
  __shared__ float qs[16][64];
  const int bh = blockIdx.y, b = bh >> 3, h = bh & 7;
  const int q0 = blockIdx.x * 16;
  const int w = threadIdx.x >> 6, lane = threadIdx.x & 63;
  const float* base = qkv + (size_t)b * NTOK * 1536;

#pragma unroll
  for (int i = 0; i < 4; i++) {
    int r = q0 + w * 4 + i;
    qs[w * 4 + i][lane] = (r < NTOK) ? base[(size_t)r * 1536 + h * 64 + lane] : 0.f;
  }

  float m[4], l[4], o[4];
#pragma unroll
  for (int i = 0; i < 4; i++) { m[i] = -1e30f; l[i] = 0.f; o[i] = 0.f; }

  for (int c = 0; c < NTOK; c += 64) {
    __syncthreads();
    for (int it = 0; it < 16; ++it) {
      int lin = it * 256 + threadIdx.x;
      int j = lin >> 6, d = lin & 63;
      int key = c + j;
      float kv = 0.f, vv = 0.f;
      if (key < NTOK) {
        kv = base[(size_t)key * 1536 + 512 + h * 64 + d];
        vv = base[(size_t)key * 1536 + 1024 + h * 64 + d];
      }
      ks[j][d] = kv; vs[j][d] = vv;
    }
    __syncthreads();
#pragma unroll
    for (int i = 0; i < 4; i++) {
      float sacc = 0.f;
#pragma unroll
      for (int d = 0; d < 64; d++)
        sacc = fmaf(qs[w * 4 + i][d], ks[lane][d], sacc);
      float sc = sacc * ATT_SCALE;
      if (c + lane >= NTOK) sc = -1e30f;
      float mc = wmax(sc);
      float mn = fmaxf(m[i], mc);
      float p = expf(sc - mn);
      if (c + lane >= NTOK) p = 0.f;
      float alpha = expf(m[i] - mn);
      float ps = wsum(p);
      l[i] = l[i] * alpha + ps;
      float acc = 0.f;
#pragma unroll
      for (int j = 0; j < 64; j++) {
        float pj = __shfl(p, j, 64);
        acc = fmaf(pj, vs[j][lane], acc);
      }
      o[i] = o[i] * alpha + acc;
      m[i] = mn;
    }
  }

#pragma unroll
  for (int i = 0; i < 4; i++) {
    int r = q0 + w * 4 + i;
    if (r < NTOK)
      out[((size_t)b * NTOK + r) * DIMM + h * 64 + lane] = o[i] / l[i];
  }
}

// ---------------------------------------------------------------------------
// Head: x[:,0] -> LN -> @ head_w + head_b -> sigmoid. One wave per batch.
// ---------------------------------------------------------------------------
__global__ __launch_bounds__(256) void head_k(
    const float* __restrict__ X, const float* __restrict__ s,
    const float* __restrict__ bln, const float* __restrict__ W,
    const float* __restrict__ bh, float* __restrict__ out)
{
  const int w = threadIdx.x >> 6, lane = threadIdx.x & 63;
  if (w >= BATCH) return;
  const float* x = X + (size_t)w * NTOK * DIMM;  // token 0 of batch w
  float4 v0 = *(const float4*)(x + lane * 8);
  float4 v1 = *(const float4*)(x + lane * 8 + 4);
  float xv[8] = {v0.x, v0.y, v0.z, v0.w, v1.x, v1.y, v1.z, v1.w};
  float sum = 0.f, sq = 0.f;
#pragma unroll
  for (int i = 0; i < 8; i++) { sum += xv[i]; sq += xv[i] * xv[i]; }
  sum = wsum(sum); sq = wsum(sq);
  const float mean = sum * (1.0f / DIMM);
  const float var  = sq * (1.0f / DIMM) - mean * mean;
  const float r    = rsqrtf(var + LN_EPS);
  float l0 = 0.f, l1 = 0.f;
#pragma unroll
  for (int i = 0; i < 8; i++) {
    int d = lane * 8 + i;
    float xn = (xv[i] - mean) * r * s[d] + bln[d];
    l0 = fmaf(xn, W[d * 2 + 0], l0);
    l1 = fmaf(xn, W[d * 2 + 1], l1);
  }
  l0 = wsum(l0); l1 = wsum(l1);
  if (lane == 0) {
    out[w * 2 + 0] = 1.0f / (1.0f + expf(-(l0 + bh[0])));
    out[w * 2 + 1] = 1.0f / (1.0f + expf(-(l1 + bh[1])));
  }
}

// ---------------------------------------------------------------------------
extern "C" void kernel_launch(void* const* d_in, const int* in_sizes, int n_in,
                              void* d_out, int out_size, void* d_ws, size_t ws_size,
                              hipStream_t stream)
{
  const float* img       = (const float*)d_in[0];
  const float* embed_w   = (const float*)d_in[1];
  const float* embed_b   = (const float*)d_in[2];
  const float* pos_emb   = (const float*)d_in[3];
  const float* cls_token = (const float*)d_in[4];
  const float* ln1_s     = (const float*)d_in[5];
  const float* ln1_b     = (const float*)d_in[6];
  const float* qkv_w     = (const float*)d_in[7];
  const float* out_w     = (const float*)d_in[8];
  const float* out_b     = (const float*)d_in[9];
  const float* ln2_s     = (const float*)d_in[10];
  const float* ln2_b     = (const float*)d_in[11];
  const float* ff_w1     = (const float*)d_in[12];
  const float* ff_b1     = (const float*)d_in[13];
  const float* ff_w2     = (const float*)d_in[14];
  const float* ff_b2     = (const float*)d_in[15];
  const float* head_ln_s = (const float*)d_in[16];
  const float* head_ln_b = (const float*)d_in[17];
  const float* head_w    = (const float*)d_in[18];
  const float* head_b    = (const float*)d_in[19];
  float* out = (float*)d_out;

  // Workspace layout (floats):
  //   x:    ROWS*DIMM          = 2,099,200
  //   hbuf: ROWS*DIMM          = 2,099,200
  //   big:  ROWS*MLPD          = 8,396,800  (qkv: first 6,297,600 |
  //                                          attn_out: last 2,099,200;
  //                                          whole region reused as ff hidden)
  // total 12,595,200 floats = 50.4 MB
  float* ws   = (float*)d_ws;
  float* x    = ws;
  float* hbuf = x + (size_t)ROWS * DIMM;
  float* big  = hbuf + (size_t)ROWS * DIMM;
  float* qkvb = big;
  float* attn_out = big + (size_t)ROWS * 1536;
  float* ffh  = big;

  dim3 blk(256);

  // Patch embed GEMM: img (4096x512) @ embed_w (512x512) + embed_b -> hbuf
  gemm_k<<<dim3(DIMM / 64, (BATCH * NPATCH) / 64), blk, 0, stream>>>(
      img, embed_w, embed_b, nullptr, hbuf, BATCH * NPATCH, DIMM, DIMM, 0);
  // x = concat(cls, hbuf) + pos_emb
  assemble_k<<<(BATCH * NTOK * DIMM + 255) / 256, blk, 0, stream>>>(
      hbuf, cls_token, pos_emb, x);

  const int mtiles = (ROWS + 63) / 64;  // 65
  for (int l = 0; l < 8; l++) {
    ln_k<<<(ROWS + 3) / 4, blk, 0, stream>>>(
        x, ln1_s + l * DIMM, ln1_b + l * DIMM, hbuf, ROWS);
    gemm_k<<<dim3(1536 / 64, mtiles), blk, 0, stream>>>(
        hbuf, qkv_w + (size_t)l * DIMM * 1536, nullptr, nullptr,
        qkvb, ROWS, 1536, DIMM, 0);
    attn_k<<<dim3((NTOK + 15) / 16, BATCH * NHEADS), blk, 0, stream>>>(
        qkvb, attn_out);
    gemm_k<<<dim3(DIMM / 64, mtiles), blk, 0, stream>>>(
        attn_out, out_w + (size_t)l * DIMM * DIMM, out_b + l * DIMM, x,
        x, ROWS, DIMM, DIMM, 0);
    ln_k<<<(ROWS + 3) / 4, blk, 0, stream>>>(
        x, ln2_s + l * DIMM, ln2_b + l * DIMM, hbuf, ROWS);
    gemm_k<<<dim3(MLPD / 64, mtiles), blk, 0, stream>>>(
        hbuf, ff_w1 + (size_t)l * DIMM * MLPD, ff_b1 + l * MLPD, nullptr,
        ffh, ROWS, MLPD, DIMM, 1);
    gemm_k<<<dim3(DIMM / 64, mtiles), blk, 0, stream>>>(
        ffh, ff_w2 + (size_t)l * MLPD * DIMM, ff_b2 + l * DIMM, x,
        x, ROWS, DIMM, MLPD, 0);
  }

  head_k<<<1, blk, 0, stream>>>(x, head_ln_s, head_ln_b, head_w, head_b, out);
}

// Round 2
// 6931.507 us; speedup vs baseline: 2.3060x; 2.3060x over previous
//
#include <hip/hip_runtime.h>
#include <math.h>

#define NHEADS   8
#define DHEAD    64
#define DIMM     512
#define MLPD     2048
#define NPATCH   1024
#define NTOK     1025
#define BATCH    4
#define ROWS     (BATCH*NTOK)   /* 4100 */
#define ATT_SCALE 0.125f
#define LN_EPS   1e-5f

__device__ __forceinline__ float wsum(float v) {
#pragma unroll
  for (int o = 32; o > 0; o >>= 1) v += __shfl_xor(v, o, 64);
  return v;
}

// ---------------------------------------------------------------------------
// Generic fp32 GEMM: C[M,N] = A[M,K] @ B[K,N] (+bias) (+gelu) (+residual)
// 64x64 tile, BK=16, 256 threads, 4x4 micro-tile per thread.
// ---------------------------------------------------------------------------
__global__ __launch_bounds__(256) void gemm_k(
    const float* __restrict__ A, const float* __restrict__ B,
    const float* __restrict__ bias, const float* __restrict__ res,
    float* __restrict__ C, int M, int N, int K, int act)
{
  __shared__ float sA[16][65];
  __shared__ float sB[16][64];
  const int tid = threadIdx.x;
  const int m0 = blockIdx.y * 64, n0 = blockIdx.x * 64;
  const int ar = tid >> 2, ak = (tid & 3) << 2;   // A tile load: row, k4
  const int bk = tid >> 4, bn = (tid & 15) << 2;  // B tile load: k, col4
  const int ty = tid >> 4, tx = tid & 15;         // compute mapping

  float acc[4][4] = {};

  for (int k0 = 0; k0 < K; k0 += 16) {
    float4 av = make_float4(0.f, 0.f, 0.f, 0.f);
    if (m0 + ar < M)
      av = *(const float4*)(A + (size_t)(m0 + ar) * K + k0 + ak);
    float4 bv = *(const float4*)(B + (size_t)(k0 + bk) * N + n0 + bn);
    __syncthreads();
    sA[ak + 0][ar] = av.x; sA[ak + 1][ar] = av.y;
    sA[ak + 2][ar] = av.z; sA[ak + 3][ar] = av.w;
    *(float4*)&sB[bk][bn] = bv;
    __syncthreads();
#pragma unroll
    for (int kk = 0; kk < 16; kk++) {
      float a[4], b[4];
#pragma unroll
      for (int i = 0; i < 4; i++) a[i] = sA[kk][ty * 4 + i];
      float4 b4 = *(const float4*)&sB[kk][tx * 4];
      b[0] = b4.x; b[1] = b4.y; b[2] = b4.z; b[3] = b4.w;
#pragma unroll
      for (int i = 0; i < 4; i++)
#pragma unroll
        for (int j = 0; j < 4; j++)
          acc[i][j] = fmaf(a[i], b[j], acc[i][j]);
    }
  }

#pragma unroll
  for (int i = 0; i < 4; i++) {
    int row = m0 + ty * 4 + i;
    if (row >= M) continue;
#pragma unroll
    for (int j = 0; j < 4; j++) {
      int col = n0 + tx * 4 + j;
      float v = acc[i][j];
      if (bias) v += bias[col];
      if (act == 1) v = 0.5f * v * (1.0f + erff(v * 0.70710678118654752f));
      if (res) v += res[(size_t)row * N + col];
      C[(size_t)row * N + col] = v;
    }
  }
}

// ---------------------------------------------------------------------------
// LayerNorm over last dim (512): one wave per row, 4 rows per block.
// ---------------------------------------------------------------------------
__global__ __launch_bounds__(256) void ln_k(
    const float* __restrict__ X, const float* __restrict__ s,
    const float* __restrict__ b, float* __restrict__ Y, int nrows)
{
  const int w = threadIdx.x >> 6, lane = threadIdx.x & 63;
  const int row = blockIdx.x * 4 + w;
  if (row >= nrows) return;
  const float* x = X + (size_t)row * DIMM;
  float4 v0 = *(const float4*)(x + lane * 8);
  float4 v1 = *(const float4*)(x + lane * 8 + 4);
  float xv[8] = {v0.x, v0.y, v0.z, v0.w, v1.x, v1.y, v1.z, v1.w};
  float sum = 0.f, sq = 0.f;
#pragma unroll
  for (int i = 0; i < 8; i++) { sum += xv[i]; sq += xv[i] * xv[i]; }
  sum = wsum(sum); sq = wsum(sq);
  const float mean = sum * (1.0f / DIMM);
  const float var  = sq * (1.0f / DIMM) - mean * mean;
  const float r    = rsqrtf(var + LN_EPS);
  float* y = Y + (size_t)row * DIMM;
#pragma unroll
  for (int i = 0; i < 8; i++) {
    int d = lane * 8 + i;
    y[d] = (xv[i] - mean) * r * s[d] + b[d];
  }
}

// ---------------------------------------------------------------------------
// Assemble x = concat(cls, patch_embed) + pos_emb
// ---------------------------------------------------------------------------
__global__ __launch_bounds__(256) void assemble_k(
    const float* __restrict__ emb, const float* __restrict__ cls,
    const float* __restrict__ pos, float* __restrict__ X)
{
  int idx = blockIdx.x * 256 + threadIdx.x;
  if (idx >= BATCH * NTOK * DIMM) return;
  int d = idx & (DIMM - 1);
  int t = (idx >> 9) % NTOK;
  int b = idx / (NTOK * DIMM);
  float v = (t == 0) ? cls[d] : emb[((size_t)b * NPATCH + (t - 1)) * DIMM + d];
  X[idx] = v + pos[(size_t)t * DIMM + d];
}

// ---------------------------------------------------------------------------
// Flash attention, register-tiled fp32.
// Block = 256 threads (16x16), handles one (b,h) and a 64-row Q tile.
// Each thread owns a 4x4 micro-tile: q-rows ty*4..+3, key/out-dim cols tx*4..+3.
// LDS: qs (Q, XOR-swizzled), ksp (K chunk swizzled, reused for P^T), vs (V).
// All hot ds_read_b128 are conflict-free (<=2-way) via group-XOR swizzle:
//   idx(row,d) = row*64 + (((d>>2) ^ (row>>2)) & 15)*4 + (d&3)
// ---------------------------------------------------------------------------
__global__ __launch_bounds__(256) void attn_k(
    const float* __restrict__ qkv, float* __restrict__ out)
{
  __shared__ float qs[64 * 64];
  __shared__ float ksp[64 * 64];   // K chunk; after S-compute, reused as P^T
  __shared__ float vs[64 * 64];    // V chunk row-major
  const int bh = blockIdx.y, b = bh >> 3, h = bh & 7;
  const int q0 = blockIdx.x * 64;
  const int tid = threadIdx.x;
  const int ty = tid >> 4, tx = tid & 15;
  const float* base = qkv + (size_t)b * NTOK * 1536;

  // Load Q tile (coalesced global, swizzled LDS store)
#pragma unroll
  for (int it = 0; it < 16; ++it) {
    int lin = it * 256 + tid;
    int r = lin >> 6, d = lin & 63;
    int gr = q0 + r;
    float v = (gr < NTOK) ? base[(size_t)gr * 1536 + h * 64 + d] : 0.f;
    qs[r * 64 + ((((d >> 2) ^ (r >> 2)) & 15) << 2) + (d & 3)] = v;
  }

  float m[4], l[4], o[4][4];
#pragma unroll
  for (int i = 0; i < 4; i++) {
    m[i] = -1e30f; l[i] = 0.f;
#pragma unroll
    for (int j = 0; j < 4; j++) o[i][j] = 0.f;
  }

  for (int c0 = 0; c0 < NTOK; c0 += 64) {
    __syncthreads();  // previous PV finished reading ksp/vs
#pragma unroll
    for (int it = 0; it < 16; ++it) {
      int lin = it * 256 + tid;
      int j = lin >> 6, d = lin & 63;
      int key = c0 + j;
      float kv = 0.f, vv = 0.f;
      if (key < NTOK) {
        kv = base[(size_t)key * 1536 + 512 + h * 64 + d];
        vv = base[(size_t)key * 1536 + 1024 + h * 64 + d];
      }
      ksp[j * 64 + ((((d >> 2) ^ (j >> 2)) & 15) << 2) + (d & 3)] = kv;
      vs[j * 64 + d] = vv;
    }
    __syncthreads();

    // S = Q K^T  (4x4 per thread, dot4 over d-groups)
    float s[4][4] = {};
#pragma unroll
    for (int g = 0; g < 16; ++g) {
      float4 a4[4], b4[4];
#pragma unroll
      for (int i = 0; i < 4; i++) {
        int r = ty * 4 + i;
        a4[i] = *(const float4*)&qs[r * 64 + (((g ^ (r >> 2)) & 15) << 2)];
      }
#pragma unroll
      for (int j = 0; j < 4; j++) {
        int c = tx * 4 + j;
        b4[j] = *(const float4*)&ksp[c * 64 + (((g ^ (c >> 2)) & 15) << 2)];
      }
#pragma unroll
      for (int i = 0; i < 4; i++)
#pragma unroll
        for (int j = 0; j < 4; j++)
          s[i][j] += a4[i].x * b4[j].x + a4[i].y * b4[j].y +
                     a4[i].z * b4[j].z + a4[i].w * b4[j].w;
    }

    // Online softmax (row stats across the 16 lanes sharing each row)
#pragma unroll
    for (int i = 0; i < 4; i++) {
      float mx = -1e30f;
#pragma unroll
      for (int j = 0; j < 4; j++) {
        float sc = s[i][j] * ATT_SCALE;
        if (c0 + tx * 4 + j >= NTOK) sc = -1e30f;
        s[i][j] = sc;
        mx = fmaxf(mx, sc);
      }
#pragma unroll
      for (int d = 1; d < 16; d <<= 1) mx = fmaxf(mx, __shfl_xor(mx, d, 64));
      float nm = fmaxf(m[i], mx);
      float alpha = __expf(m[i] - nm);
      m[i] = nm;
      float rs = 0.f;
#pragma unroll
      for (int j = 0; j < 4; j++) {
        float p = __expf(s[i][j] - nm);
        s[i][j] = p;
        rs += p;
      }
#pragma unroll
      for (int d = 1; d < 16; d <<= 1) rs += __shfl_xor(rs, d, 16);
      l[i] = l[i] * alpha + rs;
#pragma unroll
      for (int j = 0; j < 4; j++) o[i][j] *= alpha;
    }

    __syncthreads();  // all threads done reading K from ksp
    // Write P^T into ksp: p_t[k][qrow], same XOR swizzle -> conflict-free
#pragma unroll
    for (int j = 0; j < 4; j++) {
      int k = tx * 4 + j;
      float4 w = make_float4(s[0][j], s[1][j], s[2][j], s[3][j]);
      *(float4*)&ksp[k * 64 + (((ty ^ (k >> 2)) & 15) << 2)] = w;
    }
    __syncthreads();

    // O += P V  (outer product over k)
#pragma unroll 8
    for (int k = 0; k < 64; ++k) {
      float4 a4 = *(const float4*)&ksp[k * 64 + (((ty ^ (k >> 2)) & 15) << 2)];
      float4 b4 = *(const float4*)&vs[k * 64 + tx * 4];
      float a[4] = {a4.x, a4.y, a4.z, a4.w};
      float v[4] = {b4.x, b4.y, b4.z, b4.w};
#pragma unroll
      for (int i = 0; i < 4; i++)
#pragma unroll
        for (int j = 0; j < 4; j++)
          o[i][j] = fmaf(a[i], v[j], o[i][j]);
    }
  }

#pragma unroll
  for (int i = 0; i < 4; i++) {
    int r = q0 + ty * 4 + i;
    if (r < NTOK) {
      float inv = 1.0f / l[i];
      float4 w = make_float4(o[i][0] * inv, o[i][1] * inv,
                             o[i][2] * inv, o[i][3] * inv);
      *(float4*)&out[((size_t)b * NTOK + r) * DIMM + h * 64 + tx * 4] = w;
    }
  }
}

// ---------------------------------------------------------------------------
// Head: x[:,0] -> LN -> @ head_w + head_b -> sigmoid. One wave per batch.
// ---------------------------------------------------------------------------
__global__ __launch_bounds__(256) void head_k(
    const float* __restrict__ X, const float* __restrict__ s,
    const float* __restrict__ bln, const float* __restrict__ W,
    const float* __restrict__ bh, float* __restrict__ out)
{
  const int w = threadIdx.x >> 6, lane = threadIdx.x & 63;
  if (w >= BATCH) return;
  const float* x = X + (size_t)w * NTOK * DIMM;  // token 0 of batch w
  float4 v0 = *(const float4*)(x + lane * 8);
  float4 v1 = *(const float4*)(x + lane * 8 + 4);
  float xv[8] = {v0.x, v0.y, v0.z, v0.w, v1.x, v1.y, v1.z, v1.w};
  float sum = 0.f, sq = 0.f;
#pragma unroll
  for (int i = 0; i < 8; i++) { sum += xv[i]; sq += xv[i] * xv[i]; }
  sum = wsum(sum); sq = wsum(sq);
  const float mean = sum * (1.0f / DIMM);
  const float var  = sq * (1.0f / DIMM) - mean * mean;
  const float r    = rsqrtf(var + LN_EPS);
  float l0 = 0.f, l1 = 0.f;
#pragma unroll
  for (int i = 0; i < 8; i++) {
    int d = lane * 8 + i;
    float xn = (xv[i] - mean) * r * s[d] + bln[d];
    l0 = fmaf(xn, W[d * 2 + 0], l0);
    l1 = fmaf(xn, W[d * 2 + 1], l1);
  }
  l0 = wsum(l0); l1 = wsum(l1);
  if (lane == 0) {
    out[w * 2 + 0] = 1.0f / (1.0f + expf(-(l0 + bh[0])));
    out[w * 2 + 1] = 1.0f / (1.0f + expf(-(l1 + bh[1])));
  }
}

// ---------------------------------------------------------------------------
extern "C" void kernel_launch(void* const* d_in, const int* in_sizes, int n_in,
                              void* d_out, int out_size, void* d_ws, size_t ws_size,
                              hipStream_t stream)
{
  const float* img       = (const float*)d_in[0];
  const float* embed_w   = (const float*)d_in[1];
  const float* embed_b   = (const float*)d_in[2];
  const float* pos_emb   = (const float*)d_in[3];
  const float* cls_token = (const float*)d_in[4];
  const float* ln1_s     = (const float*)d_in[5];
  const float* ln1_b     = (const float*)d_in[6];
  const float* qkv_w     = (const float*)d_in[7];
  const float* out_w     = (const float*)d_in[8];
  const float* out_b     = (const float*)d_in[9];
  const float* ln2_s     = (const float*)d_in[10];
  const float* ln2_b     = (const float*)d_in[11];
  const float* ff_w1     = (const float*)d_in[12];
  const float* ff_b1     = (const float*)d_in[13];
  const float* ff_w2     = (const float*)d_in[14];
  const float* ff_b2     = (const float*)d_in[15];
  const float* head_ln_s = (const float*)d_in[16];
  const float* head_ln_b = (const float*)d_in[17];
  const float* head_w    = (const float*)d_in[18];
  const float* head_b    = (const float*)d_in[19];
  float* out = (float*)d_out;

  float* ws   = (float*)d_ws;
  float* x    = ws;
  float* hbuf = x + (size_t)ROWS * DIMM;
  float* big  = hbuf + (size_t)ROWS * DIMM;
  float* qkvb = big;
  float* attn_out = big + (size_t)ROWS * 1536;
  float* ffh  = big;

  dim3 blk(256);

  gemm_k<<<dim3(DIMM / 64, (BATCH * NPATCH) / 64), blk, 0, stream>>>(
      img, embed_w, embed_b, nullptr, hbuf, BATCH * NPATCH, DIMM, DIMM, 0);
  assemble_k<<<(BATCH * NTOK * DIMM + 255) / 256, blk, 0, stream>>>(
      hbuf, cls_token, pos_emb, x);

  const int mtiles = (ROWS + 63) / 64;  // 65
  for (int l = 0; l < 8; l++) {
    ln_k<<<(ROWS + 3) / 4, blk, 0, stream>>>(
        x, ln1_s + l * DIMM, ln1_b + l * DIMM, hbuf, ROWS);
    gemm_k<<<dim3(1536 / 64, mtiles), blk, 0, stream>>>(
        hbuf, qkv_w + (size_t)l * DIMM * 1536, nullptr, nullptr,
        qkvb, ROWS, 1536, DIMM, 0);
    attn_k<<<dim3((NTOK + 63) / 64, BATCH * NHEADS), blk, 0, stream>>>(
        qkvb, attn_out);
    gemm_k<<<dim3(DIMM / 64, mtiles), blk, 0, stream>>>(
        attn_out, out_w + (size_t)l * DIMM * DIMM, out_b + l * DIMM, x,
        x, ROWS, DIMM, DIMM, 0);
    ln_k<<<(ROWS + 3) / 4, blk, 0, stream>>>(
        x, ln2_s + l * DIMM, ln2_b + l * DIMM, hbuf, ROWS);
    gemm_k<<<dim3(MLPD / 64, mtiles), blk, 0, stream>>>(
        hbuf, ff_w1 + (size_t)l * DIMM * MLPD, ff_b1 + l * MLPD, nullptr,
        ffh, ROWS, MLPD, DIMM, 1);
    gemm_k<<<dim3(DIMM / 64, mtiles), blk, 0, stream>>>(
        ffh, ff_w2 + (size_t)l * MLPD * DIMM, ff_b2 + l * DIMM, x,
        x, ROWS, DIMM, MLPD, 0);
  }

  head_k<<<1, blk, 0, stream>>>(x, head_ln_s, head_ln_b, head_w, head_b, out);
}

// Round 3
// 2077.061 us; speedup vs baseline: 7.6954x; 3.3372x over previous
//
#include <hip/hip_runtime.h>
#include <math.h>
#include <stdint.h>

#define NHEADS   8
#define DHEAD    64
#define DIMM     512
#define MLPD     2048
#define NPATCH   1024
#define NTOK     1025
#define BATCH    4
#define ROWS     (BATCH*NTOK)   /* 4100 */
#define ATT_SCALE 0.125f
#define LN_EPS   1e-5f

typedef __attribute__((ext_vector_type(8))) short short8;
typedef __attribute__((ext_vector_type(4))) float f32x4;

__device__ __forceinline__ unsigned short f2bf(float f) {
  union { float f; unsigned u; } c; c.f = f;
  unsigned u = c.u;
  return (unsigned short)((u + 0x7fffu + ((u >> 16) & 1u)) >> 16);
}

__device__ __forceinline__ float wsum(float v) {
#pragma unroll
  for (int o = 32; o > 0; o >>= 1) v += __shfl_xor(v, o, 64);
  return v;
}

// async 16B/lane global->LDS. lds base must be wave-uniform; dest = base+lane*16.
__device__ __forceinline__ void gl_lds16(const void* g, const void* l) {
  __builtin_amdgcn_global_load_lds(
      (const __attribute__((address_space(1))) unsigned int*)(uintptr_t)g,
      (__attribute__((address_space(3))) unsigned int*)(unsigned int)(uintptr_t)l,
      16, 0, 0);
}

// ---------------------------------------------------------------------------
// bf16 MFMA GEMM: C[M,N] = A[M,K] @ Bt[N,K]^T (+bias)(+gelu)(+res), out fp32/bf16
// 128x128 tile, BK=64, 256 thr (4 waves, each 64x64), 16x16x32 MFMA.
// LDS layout: [row][64] bf16 rows of 128B; k-group g (8 bf16) stored at
// physical slot g ^ (row&7)  -> conflict-free b128 frags + valid lds-DMA order.
// flags: bit0 = gelu, bit1 = bf16 output.
// ---------------------------------------------------------------------------
__global__ __launch_bounds__(256) void mgemm_k(
    const unsigned short* __restrict__ A, const unsigned short* __restrict__ Bt,
    const float* __restrict__ bias, const float* __restrict__ res,
    void* __restrict__ Cout, int M, int N, int K, int flags)
{
  __shared__ unsigned short sA[128 * 64];
  __shared__ unsigned short sB[128 * 64];
  const int tid = threadIdx.x;
  const int w = tid >> 6, lane = tid & 63;
  const int quad = lane >> 4, l15 = lane & 15;
  const int m0 = blockIdx.y * 128, n0 = blockIdx.x * 128;
  const int wr = (w >> 1) * 64, wc = (w & 1) * 64;
  const int lrow = lane >> 3;               // row within 8-row DMA group
  const int lkg = (lane & 7) ^ lrow;        // logical k-group this lane fetches

  f32x4 acc[4][4];
#pragma unroll
  for (int i = 0; i < 4; i++)
#pragma unroll
    for (int j = 0; j < 4; j++) { f32x4 z = {0.f, 0.f, 0.f, 0.f}; acc[i][j] = z; }

  for (int k0 = 0; k0 < K; k0 += 64) {
#pragma unroll
    for (int g = 0; g < 4; g++) {
      int grp = w * 4 + g;
      int ar = m0 + grp * 8 + lrow; ar = ar < M ? ar : M - 1;  // clamp: garbage rows never stored
      gl_lds16(A + (size_t)ar * K + k0 + lkg * 8, &sA[grp * 512]);
      int br = n0 + grp * 8 + lrow;                            // N is always a multiple of 128
      gl_lds16(Bt + (size_t)br * K + k0 + lkg * 8, &sB[grp * 512]);
    }
    __syncthreads();
#pragma unroll
    for (int kk = 0; kk < 2; kk++) {
      short8 af[4], bfr[4];
#pragma unroll
      for (int i = 0; i < 4; i++) {
        int r = wr + i * 16 + l15;
        af[i] = *(const short8*)&sA[r * 64 + (((kk * 4 + quad) ^ (lane & 7)) << 3)];
      }
#pragma unroll
      for (int j = 0; j < 4; j++) {
        int r = wc + j * 16 + l15;
        bfr[j] = *(const short8*)&sB[r * 64 + (((kk * 4 + quad) ^ (lane & 7)) << 3)];
      }
#pragma unroll
      for (int i = 0; i < 4; i++)
#pragma unroll
        for (int j = 0; j < 4; j++)
          acc[i][j] = __builtin_amdgcn_mfma_f32_16x16x32_bf16(af[i], bfr[j], acc[i][j], 0, 0, 0);
    }
    __syncthreads();
  }

  const bool do_gelu = flags & 1;
  const bool out_bf  = flags & 2;
#pragma unroll
  for (int i = 0; i < 4; i++) {
#pragma unroll
    for (int rg = 0; rg < 4; rg++) {
      int row = m0 + wr + i * 16 + quad * 4 + rg;
      if (row >= M) continue;
#pragma unroll
      for (int j = 0; j < 4; j++) {
        int col = n0 + wc + j * 16 + l15;
        float v = acc[i][j][rg];
        if (bias) v += bias[col];
        if (do_gelu) v = 0.5f * v * (1.0f + erff(v * 0.70710678118654752f));
        if (res) v += res[(size_t)row * N + col];
        if (out_bf) ((unsigned short*)Cout)[(size_t)row * N + col] = f2bf(v);
        else        ((float*)Cout)[(size_t)row * N + col] = v;
      }
    }
  }
}

// ---------------------------------------------------------------------------
// MFMA flash attention, bf16 in (qkv [B,NTOK,1536]) / bf16 out ([B,NTOK,512]).
// Block: one (b,h), 64 q-rows, 4 waves (16 q-rows each). 64-key chunks.
// S = Q K^T and O += P V via 16x16x32 MFMA; softmax fp32 in registers.
// ---------------------------------------------------------------------------
__global__ __launch_bounds__(256) void attn_k(
    const unsigned short* __restrict__ qkv, unsigned short* __restrict__ out)
{
  __shared__ unsigned short qs[64 * 64];
  __shared__ unsigned short ks[64 * 64];
  __shared__ unsigned short vt[64 * 64];   // V^T: [d][key]
  __shared__ unsigned short ps[64 * 64];   // P in A-operand layout
  const int bh = blockIdx.y, b = bh >> 3, h = bh & 7;
  const int q0 = blockIdx.x * 64;
  const int tid = threadIdx.x, w = tid >> 6, lane = tid & 63;
  const int quad = lane >> 4, l15 = lane & 15;
  const int lrow = lane >> 3, lkg = (lane & 7) ^ lrow;
  const unsigned short* base = qkv + (size_t)(b * NTOK) * 1536;

  // stage Q (64 rows x 64 d): 8 DMA instrs, 2 per wave
#pragma unroll
  for (int g = 0; g < 2; g++) {
    int grp = w * 2 + g;
    int tok = q0 + grp * 8 + lrow; tok = tok < NTOK ? tok : NTOK - 1;
    gl_lds16(base + (size_t)tok * 1536 + h * 64 + lkg * 8, &qs[grp * 512]);
  }

  f32x4 Oa[4];
#pragma unroll
  for (int n = 0; n < 4; n++) { f32x4 z = {0.f, 0.f, 0.f, 0.f}; Oa[n] = z; }
  float mst[4], lst[4];
#pragma unroll
  for (int r = 0; r < 4; r++) { mst[r] = -1e30f; lst[r] = 0.f; }

  for (int c0 = 0; c0 < NTOK; c0 += 64) {
    __syncthreads();   // prev chunk's readers of ks/vt done
    // stage K chunk
#pragma unroll
    for (int g = 0; g < 2; g++) {
      int grp = w * 2 + g;
      int tok = c0 + grp * 8 + lrow; tok = tok < NTOK ? tok : NTOK - 1;
      gl_lds16(base + (size_t)tok * 1536 + 512 + h * 64 + lkg * 8, &ks[grp * 512]);
    }
    // stage V transposed: thread = (key=lane, d-group), 2 iters
#pragma unroll
    for (int it = 0; it < 2; ++it) {
      int d0 = w * 8 + it * 32;
      int tok = c0 + lane; tok = tok < NTOK ? tok : NTOK - 1;
      alignas(16) unsigned short vv[8];
      *(uint4*)vv = *(const uint4*)(base + (size_t)tok * 1536 + 1024 + h * 64 + d0);
#pragma unroll
      for (int i = 0; i < 8; i++) {
        int d = d0 + i;
        vt[d * 64 + ((((lane >> 3) ^ (d & 7)) & 7) << 3) + (lane & 7)] = vv[i];
      }
    }
    __syncthreads();

    // S = Q K^T : 16 q-rows x 64 keys per wave
    short8 aq[2];
#pragma unroll
    for (int kk = 0; kk < 2; kk++)
      aq[kk] = *(const short8*)&qs[(w * 16 + l15) * 64 + (((kk * 4 + quad) ^ (lane & 7)) << 3)];
    f32x4 sa[4];
#pragma unroll
    for (int n = 0; n < 4; n++) {
      f32x4 s = {0.f, 0.f, 0.f, 0.f};
#pragma unroll
      for (int kk = 0; kk < 2; kk++) {
        short8 bk = *(const short8*)&ks[(n * 16 + l15) * 64 + (((kk * 4 + quad) ^ (lane & 7)) << 3)];
        s = __builtin_amdgcn_mfma_f32_16x16x32_bf16(aq[kk], bk, s, 0, 0, 0);
      }
      sa[n] = s;
    }

    // scale + mask + online softmax (row = quad*4+reg; reduce over 16 lanes)
#pragma unroll
    for (int n = 0; n < 4; n++) {
      bool oob = (c0 + n * 16 + l15) >= NTOK;
#pragma unroll
      for (int rg = 0; rg < 4; rg++) {
        float sc = sa[n][rg] * ATT_SCALE;
        sa[n][rg] = oob ? -1e30f : sc;
      }
    }
    float alpha[4];
#pragma unroll
    for (int rg = 0; rg < 4; rg++) {
      float mx = fmaxf(fmaxf(sa[0][rg], sa[1][rg]), fmaxf(sa[2][rg], sa[3][rg]));
#pragma unroll
      for (int o = 1; o < 16; o <<= 1) mx = fmaxf(mx, __shfl_xor(mx, o, 64));
      float nm = fmaxf(mst[rg], mx);
      alpha[rg] = __expf(mst[rg] - nm);
      mst[rg] = nm;
      float rs = 0.f;
#pragma unroll
      for (int n = 0; n < 4; n++) {
        float p = __expf(sa[n][rg] - nm);
        sa[n][rg] = p;
        rs += p;
      }
#pragma unroll
      for (int o = 1; o < 16; o <<= 1) rs += __shfl_xor(rs, o, 64);
      lst[rg] = lst[rg] * alpha[rg] + rs;
    }

    // P -> LDS in A-operand layout (own-wave rows only; in-wave dep, no barrier)
#pragma unroll
    for (int n = 0; n < 4; n++)
#pragma unroll
      for (int rg = 0; rg < 4; rg++) {
        int r = quad * 4 + rg;          // local q-row 0..15
        int key = n * 16 + l15;
        int row = w * 16 + r;
        ps[row * 64 + ((((key >> 3) ^ (row & 7)) & 7) << 3) + (key & 7)] = f2bf(sa[n][rg]);
      }

    // O = O*alpha + P V
    short8 ap[2];
#pragma unroll
    for (int kk = 0; kk < 2; kk++)
      ap[kk] = *(const short8*)&ps[(w * 16 + l15) * 64 + (((kk * 4 + quad) ^ (lane & 7)) << 3)];
#pragma unroll
    for (int n = 0; n < 4; n++) {
      f32x4 o = Oa[n];
#pragma unroll
      for (int rg = 0; rg < 4; rg++) o[rg] *= alpha[rg];
#pragma unroll
      for (int kk = 0; kk < 2; kk++) {
        short8 bv = *(const short8*)&vt[(n * 16 + l15) * 64 + (((kk * 4 + quad) ^ (lane & 7)) << 3)];
        o = __builtin_amdgcn_mfma_f32_16x16x32_bf16(ap[kk], bv, o, 0, 0, 0);
      }
      Oa[n] = o;
    }
  }

#pragma unroll
  for (int n = 0; n < 4; n++)
#pragma unroll
    for (int rg = 0; rg < 4; rg++) {
      int tok = q0 + w * 16 + quad * 4 + rg;
      if (tok < NTOK)
        out[(size_t)(b * NTOK + tok) * DIMM + h * 64 + n * 16 + l15] =
            f2bf(Oa[n][rg] / lst[rg]);
    }
}

// ---------------------------------------------------------------------------
// LayerNorm (512): one wave per row, fp32 in -> bf16 out.
// ---------------------------------------------------------------------------
__global__ __launch_bounds__(256) void ln_k(
    const float* __restrict__ X, const float* __restrict__ s,
    const float* __restrict__ b, unsigned short* __restrict__ Y, int nrows)
{
  const int w = threadIdx.x >> 6, lane = threadIdx.x & 63;
  const int row = blockIdx.x * 4 + w;
  if (row >= nrows) return;
  const float* x = X + (size_t)row * DIMM;
  float4 v0 = *(const float4*)(x + lane * 8);
  float4 v1 = *(const float4*)(x + lane * 8 + 4);
  float xv[8] = {v0.x, v0.y, v0.z, v0.w, v1.x, v1.y, v1.z, v1.w};
  float sum = 0.f, sq = 0.f;
#pragma unroll
  for (int i = 0; i < 8; i++) { sum += xv[i]; sq += xv[i] * xv[i]; }
  sum = wsum(sum); sq = wsum(sq);
  const float mean = sum * (1.0f / DIMM);
  const float var  = sq * (1.0f / DIMM) - mean * mean;
  const float r    = rsqrtf(var + LN_EPS);
  alignas(16) unsigned short tmp[8];
#pragma unroll
  for (int i = 0; i < 8; i++) {
    int d = lane * 8 + i;
    tmp[i] = f2bf((xv[i] - mean) * r * s[d] + b[d]);
  }
  *(uint4*)&Y[(size_t)row * DIMM + lane * 8] = *(const uint4*)tmp;
}

// ---------------------------------------------------------------------------
__global__ __launch_bounds__(256) void assemble_k(
    const float* __restrict__ emb, const float* __restrict__ cls,
    const float* __restrict__ pos, float* __restrict__ X)
{
  int idx = blockIdx.x * 256 + threadIdx.x;
  if (idx >= BATCH * NTOK * DIMM) return;
  int d = idx & (DIMM - 1);
  int t = (idx >> 9) % NTOK;
  int b = idx / (NTOK * DIMM);
  float v = (t == 0) ? cls[d] : emb[((size_t)b * NPATCH + (t - 1)) * DIMM + d];
  X[idx] = v + pos[(size_t)t * DIMM + d];
}

// cast fp32 -> bf16, 4 elems/thread
__global__ __launch_bounds__(256) void cast_k(
    const float* __restrict__ X, unsigned short* __restrict__ Y, int n4)
{
  int i = blockIdx.x * 256 + threadIdx.x;
  if (i >= n4) return;
  float4 v = ((const float4*)X)[i];
  alignas(8) unsigned short o[4] = {f2bf(v.x), f2bf(v.y), f2bf(v.z), f2bf(v.w)};
  ((uint2*)Y)[i] = *(const uint2*)o;
}

// transpose + cast: W[z][K][N] fp32 -> Wt[z][N][K] bf16. 32x32 LDS tiles.
__global__ __launch_bounds__(256) void tcast_k(
    const float* __restrict__ W, unsigned short* __restrict__ Wt, int K, int N)
{
  __shared__ float t[32][33];
  const size_t off = (size_t)blockIdx.z * K * N;
  W += off; Wt += off;
  int n0 = blockIdx.x * 32, k0 = blockIdx.y * 32;
  int tx = threadIdx.x & 31, ty = threadIdx.x >> 5;
#pragma unroll
  for (int i = 0; i < 4; i++)
    t[ty + 8 * i][tx] = W[(size_t)(k0 + ty + 8 * i) * N + n0 + tx];
  __syncthreads();
#pragma unroll
  for (int i = 0; i < 4; i++) {
    int n = ty + 8 * i;
    Wt[(size_t)(n0 + n) * K + k0 + tx] = f2bf(t[tx][n]);
  }
}

// ---------------------------------------------------------------------------
__global__ __launch_bounds__(256) void head_k(
    const float* __restrict__ X, const float* __restrict__ s,
    const float* __restrict__ bln, const float* __restrict__ W,
    const float* __restrict__ bh, float* __restrict__ out)
{
  const int w = threadIdx.x >> 6, lane = threadIdx.x & 63;
  if (w >= BATCH) return;
  const float* x = X + (size_t)w * NTOK * DIMM;  // token 0 of batch w
  float4 v0 = *(const float4*)(x + lane * 8);
  float4 v1 = *(const float4*)(x + lane * 8 + 4);
  float xv[8] = {v0.x, v0.y, v0.z, v0.w, v1.x, v1.y, v1.z, v1.w};
  float sum = 0.f, sq = 0.f;
#pragma unroll
  for (int i = 0; i < 8; i++) { sum += xv[i]; sq += xv[i] * xv[i]; }
  sum = wsum(sum); sq = wsum(sq);
  const float mean = sum * (1.0f / DIMM);
  const float var  = sq * (1.0f / DIMM) - mean * mean;
  const float r    = rsqrtf(var + LN_EPS);
  float l0 = 0.f, l1 = 0.f;
#pragma unroll
  for (int i = 0; i < 8; i++) {
    int d = lane * 8 + i;
    float xn = (xv[i] - mean) * r * s[d] + bln[d];
    l0 = fmaf(xn, W[d * 2 + 0], l0);
    l1 = fmaf(xn, W[d * 2 + 1], l1);
  }
  l0 = wsum(l0); l1 = wsum(l1);
  if (lane == 0) {
    out[w * 2 + 0] = 1.0f / (1.0f + expf(-(l0 + bh[0])));
    out[w * 2 + 1] = 1.0f / (1.0f + expf(-(l1 + bh[1])));
  }
}

// ---------------------------------------------------------------------------
extern "C" void kernel_launch(void* const* d_in, const int* in_sizes, int n_in,
                              void* d_out, int out_size, void* d_ws, size_t ws_size,
                              hipStream_t stream)
{
  const float* img       = (const float*)d_in[0];
  const float* embed_w   = (const float*)d_in[1];
  const float* embed_b   = (const float*)d_in[2];
  const float* pos_emb   = (const float*)d_in[3];
  const float* cls_token = (const float*)d_in[4];
  const float* ln1_s     = (const float*)d_in[5];
  const float* ln1_b     = (const float*)d_in[6];
  const float* qkv_w     = (const float*)d_in[7];
  const float* out_w     = (const float*)d_in[8];
  const float* out_b     = (const float*)d_in[9];
  const float* ln2_s     = (const float*)d_in[10];
  const float* ln2_b     = (const float*)d_in[11];
  const float* ff_w1     = (const float*)d_in[12];
  const float* ff_b1     = (const float*)d_in[13];
  const float* ff_w2     = (const float*)d_in[14];
  const float* ff_b2     = (const float*)d_in[15];
  const float* head_ln_s = (const float*)d_in[16];
  const float* head_ln_b = (const float*)d_in[17];
  const float* head_w    = (const float*)d_in[18];
  const float* head_b    = (const float*)d_in[19];
  float* out = (float*)d_out;

  char* p = (char*)d_ws;
  auto alloc = [&](size_t bytes) { char* r = p; p += (bytes + 255) & ~(size_t)255; return r; };

  unsigned short* wt_embed = (unsigned short*)alloc((size_t)512 * 512 * 2);
  unsigned short* wt_qkv   = (unsigned short*)alloc((size_t)8 * 1536 * 512 * 2);
  unsigned short* wt_out   = (unsigned short*)alloc((size_t)8 * 512 * 512 * 2);
  unsigned short* wt_ff1   = (unsigned short*)alloc((size_t)8 * 2048 * 512 * 2);
  unsigned short* wt_ff2   = (unsigned short*)alloc((size_t)8 * 512 * 2048 * 2);
  unsigned short* img_bf   = (unsigned short*)alloc((size_t)4096 * 512 * 2);
  float*          x        = (float*)alloc((size_t)ROWS * DIMM * 4);
  unsigned short* h        = (unsigned short*)alloc((size_t)ROWS * DIMM * 2);
  char*           big      = alloc((size_t)ROWS * MLPD * 2);
  unsigned short* qkvb     = (unsigned short*)big;
  unsigned short* attn_out = (unsigned short*)(big + (size_t)ROWS * 1536 * 2);
  unsigned short* ffh      = (unsigned short*)big;
  float*          embuf    = (float*)big;

  dim3 blk(256);

  // ---- prepass: cast img, transpose+cast weights to bf16 [N][K] ----
  cast_k<<<(4096 * 512 / 4 + 255) / 256, blk, 0, stream>>>(img, img_bf, 4096 * 512 / 4);
  tcast_k<<<dim3(16, 16, 1), blk, 0, stream>>>(embed_w, wt_embed, 512, 512);
  tcast_k<<<dim3(48, 16, 8), blk, 0, stream>>>(qkv_w, wt_qkv, 512, 1536);
  tcast_k<<<dim3(16, 16, 8), blk, 0, stream>>>(out_w, wt_out, 512, 512);
  tcast_k<<<dim3(64, 16, 8), blk, 0, stream>>>(ff_w1, wt_ff1, 512, 2048);
  tcast_k<<<dim3(16, 64, 8), blk, 0, stream>>>(ff_w2, wt_ff2, 2048, 512);

  // ---- patch embed + assemble ----
  mgemm_k<<<dim3(4, 32), blk, 0, stream>>>(
      img_bf, wt_embed, embed_b, nullptr, embuf, 4096, 512, 512, 0);
  assemble_k<<<(BATCH * NTOK * DIMM + 255) / 256, blk, 0, stream>>>(
      embuf, cls_token, pos_emb, x);

  const int mt = (ROWS + 127) / 128;  // 33
  for (int l = 0; l < 8; l++) {
    ln_k<<<(ROWS + 3) / 4, blk, 0, stream>>>(
        x, ln1_s + l * DIMM, ln1_b + l * DIMM, h, ROWS);
    mgemm_k<<<dim3(12, mt), blk, 0, stream>>>(
        h, wt_qkv + (size_t)l * 1536 * 512, nullptr, nullptr,
        qkvb, ROWS, 1536, 512, 2);
    attn_k<<<dim3((NTOK + 63) / 64, BATCH * NHEADS), blk, 0, stream>>>(
        qkvb, attn_out);
    mgemm_k<<<dim3(4, mt), blk, 0, stream>>>(
        attn_out, wt_out + (size_t)l * 512 * 512, out_b + l * DIMM, x,
        x, ROWS, 512, 512, 0);
    ln_k<<<(ROWS + 3) / 4, blk, 0, stream>>>(
        x, ln2_s + l * DIMM, ln2_b + l * DIMM, h, ROWS);
    mgemm_k<<<dim3(16, mt), blk, 0, stream>>>(
        h, wt_ff1 + (size_t)l * 2048 * 512, ff_b1 + l * MLPD, nullptr,
        ffh, ROWS, 2048, 512, 1 | 2);
    mgemm_k<<<dim3(4, mt), blk, 0, stream>>>(
        ffh, wt_ff2 + (size_t)l * 512 * 2048, ff_b2 + l * DIMM, x,
        x, ROWS, 512, 2048, 0);
  }

  head_k<<<1, blk, 0, stream>>>(x, head_ln_s, head_ln_b, head_w, head_b, out);
}

// Round 4
// 1583.314 us; speedup vs baseline: 10.0952x; 1.3118x over previous
//
#include <hip/hip_runtime.h>
#include <math.h>
#include <stdint.h>

#define NHEADS   8
#define DHEAD    64
#define DIMM     512
#define MLPD     2048
#define NPATCH   1024
#define NTOK     1025
#define BATCH    4
#define ROWS     (BATCH*NTOK)   /* 4100 */
#define ATT_SCALE 0.125f
#define LN_EPS   1e-5f

typedef __attribute__((ext_vector_type(8))) short short8;
typedef __attribute__((ext_vector_type(4))) float f32x4;

__device__ __forceinline__ unsigned short f2bf(float f) {
  union { float f; unsigned u; } c; c.f = f;
  unsigned u = c.u;
  return (unsigned short)((u + 0x7fffu + ((u >> 16) & 1u)) >> 16);
}

__device__ __forceinline__ float wsum(float v) {
#pragma unroll
  for (int o = 32; o > 0; o >>= 1) v += __shfl_xor(v, o, 64);
  return v;
}

// async 16B/lane global->LDS. lds base must be wave-uniform; dest = base+lane*16.
__device__ __forceinline__ void gl_lds16(const void* g, const void* l) {
  __builtin_amdgcn_global_load_lds(
      (const __attribute__((address_space(1))) unsigned int*)(uintptr_t)g,
      (__attribute__((address_space(3))) unsigned int*)(unsigned int)(uintptr_t)l,
      16, 0, 0);
}

// ---------------------------------------------------------------------------
// bf16 MFMA GEMM: C[M,N] = A[M,K] @ Bt[N,K]^T (+bias)(+gelu)(+res), out f32/bf16
// Tile TM x TN, BK=64, 256 thr = 4 waves in WR x WC layout; 16x16x32 MFMA.
// LDS rows of 64 bf16 (128B); k-group g (8 bf16) of row r stored at physical
// slot g ^ (r&7) -> DMA-order-valid + conflict-free b128 fragment reads.
// flags: bit0 = gelu, bit1 = bf16 output.
// Tile choice per call site = occupancy lever: N=512 GEMMs need 64x64 tiles
// (520 blocks) or half the chip idles (R3 counters: 132 blocks -> 4.9% occ).
// ---------------------------------------------------------------------------
template <int TM, int TN, int WR, int WC>
__global__ __launch_bounds__(256) void mgemm_k(
    const unsigned short* __restrict__ A, const unsigned short* __restrict__ Bt,
    const float* __restrict__ bias, const float* __restrict__ res,
    void* __restrict__ Cout, int M, int N, int K, int flags)
{
  constexpr int AF = TM / WR / 16;   // A fragments per wave
  constexpr int BF = TN / WC / 16;   // B fragments per wave
  constexpr int AG = TM / 32;        // A DMA groups per wave (8 rows each)
  constexpr int BG = TN / 32;
  __shared__ unsigned short sA[TM * 64];
  __shared__ unsigned short sB[TN * 64];
  const int tid = threadIdx.x;
  const int w = tid >> 6, lane = tid & 63;
  const int quad = lane >> 4, l15 = lane & 15;
  const int m0 = blockIdx.y * TM, n0 = blockIdx.x * TN;
  const int wrow = (w / WC) * (TM / WR);
  const int wcol = (w % WC) * (TN / WC);
  const int lrow = lane >> 3;               // row within 8-row DMA group
  const int lkg = (lane & 7) ^ lrow;        // logical k-group this lane fetches

  f32x4 acc[AF][BF];
#pragma unroll
  for (int i = 0; i < AF; i++)
#pragma unroll
    for (int j = 0; j < BF; j++) { f32x4 z = {0.f, 0.f, 0.f, 0.f}; acc[i][j] = z; }

  for (int k0 = 0; k0 < K; k0 += 64) {
#pragma unroll
    for (int g = 0; g < AG; g++) {
      int grp = w * AG + g;
      int ar = m0 + grp * 8 + lrow; ar = ar < M ? ar : M - 1;  // clamp; junk rows unused
      gl_lds16(A + (size_t)ar * K + k0 + lkg * 8, &sA[grp * 512]);
    }
#pragma unroll
    for (int g = 0; g < BG; g++) {
      int grp = w * BG + g;
      int br = n0 + grp * 8 + lrow;                            // N % TN == 0 always
      gl_lds16(Bt + (size_t)br * K + k0 + lkg * 8, &sB[grp * 512]);
    }
    __syncthreads();
#pragma unroll
    for (int kk = 0; kk < 2; kk++) {
      short8 af[AF], bfr[BF];
#pragma unroll
      for (int i = 0; i < AF; i++) {
        int r = wrow + i * 16 + l15;
        af[i] = *(const short8*)&sA[r * 64 + (((kk * 4 + quad) ^ (lane & 7)) << 3)];
      }
#pragma unroll
      for (int j = 0; j < BF; j++) {
        int r = wcol + j * 16 + l15;
        bfr[j] = *(const short8*)&sB[r * 64 + (((kk * 4 + quad) ^ (lane & 7)) << 3)];
      }
#pragma unroll
      for (int i = 0; i < AF; i++)
#pragma unroll
        for (int j = 0; j < BF; j++)
          acc[i][j] = __builtin_amdgcn_mfma_f32_16x16x32_bf16(af[i], bfr[j], acc[i][j], 0, 0, 0);
    }
    __syncthreads();
  }

  const bool do_gelu = flags & 1;
  const bool out_bf  = flags & 2;
#pragma unroll
  for (int i = 0; i < AF; i++) {
#pragma unroll
    for (int rg = 0; rg < 4; rg++) {
      int row = m0 + wrow + i * 16 + quad * 4 + rg;
      if (row >= M) continue;
#pragma unroll
      for (int j = 0; j < BF; j++) {
        int col = n0 + wcol + j * 16 + l15;
        float v = acc[i][j][rg];
        if (bias) v += bias[col];
        if (do_gelu) v = 0.5f * v * (1.0f + erff(v * 0.70710678118654752f));
        if (res) v += res[(size_t)row * N + col];
        if (out_bf) ((unsigned short*)Cout)[(size_t)row * N + col] = f2bf(v);
        else        ((float*)Cout)[(size_t)row * N + col] = v;
      }
    }
  }
}

// ---------------------------------------------------------------------------
// MFMA flash attention, bf16 in (qkv [B,NTOK,1536]) / bf16 out ([B,NTOK,512]).
// Block: one (b,h), 64 q-rows, 4 waves (16 q-rows each). 64-key chunks.
// ---------------------------------------------------------------------------
__global__ __launch_bounds__(256) void attn_k(
    const unsigned short* __restrict__ qkv, unsigned short* __restrict__ out)
{
  __shared__ unsigned short qs[64 * 64];
  __shared__ unsigned short ks[64 * 64];
  __shared__ unsigned short vt[64 * 64];   // V^T: [d][key]
  __shared__ unsigned short ps[64 * 64];   // P in A-operand layout
  const int bh = blockIdx.y, b = bh >> 3, h = bh & 7;
  const int q0 = blockIdx.x * 64;
  const int tid = threadIdx.x, w = tid >> 6, lane = tid & 63;
  const int quad = lane >> 4, l15 = lane & 15;
  const int lrow = lane >> 3, lkg = (lane & 7) ^ lrow;
  const unsigned short* base = qkv + (size_t)(b * NTOK) * 1536;

#pragma unroll
  for (int g = 0; g < 2; g++) {
    int grp = w * 2 + g;
    int tok = q0 + grp * 8 + lrow; tok = tok < NTOK ? tok : NTOK - 1;
    gl_lds16(base + (size_t)tok * 1536 + h * 64 + lkg * 8, &qs[grp * 512]);
  }

  f32x4 Oa[4];
#pragma unroll
  for (int n = 0; n < 4; n++) { f32x4 z = {0.f, 0.f, 0.f, 0.f}; Oa[n] = z; }
  float mst[4], lst[4];
#pragma unroll
  for (int r = 0; r < 4; r++) { mst[r] = -1e30f; lst[r] = 0.f; }

  for (int c0 = 0; c0 < NTOK; c0 += 64) {
    __syncthreads();
#pragma unroll
    for (int g = 0; g < 2; g++) {
      int grp = w * 2 + g;
      int tok = c0 + grp * 8 + lrow; tok = tok < NTOK ? tok : NTOK - 1;
      gl_lds16(base + (size_t)tok * 1536 + 512 + h * 64 + lkg * 8, &ks[grp * 512]);
    }
#pragma unroll
    for (int it = 0; it < 2; ++it) {
      int d0 = w * 8 + it * 32;
      int tok = c0 + lane; tok = tok < NTOK ? tok : NTOK - 1;
      alignas(16) unsigned short vv[8];
      *(uint4*)vv = *(const uint4*)(base + (size_t)tok * 1536 + 1024 + h * 64 + d0);
#pragma unroll
      for (int i = 0; i < 8; i++) {
        int d = d0 + i;
        vt[d * 64 + ((((lane >> 3) ^ (d & 7)) & 7) << 3) + (lane & 7)] = vv[i];
      }
    }
    __syncthreads();

    short8 aq[2];
#pragma unroll
    for (int kk = 0; kk < 2; kk++)
      aq[kk] = *(const short8*)&qs[(w * 16 + l15) * 64 + (((kk * 4 + quad) ^ (lane & 7)) << 3)];
    f32x4 sa[4];
#pragma unroll
    for (int n = 0; n < 4; n++) {
      f32x4 s = {0.f, 0.f, 0.f, 0.f};
#pragma unroll
      for (int kk = 0; kk < 2; kk++) {
        short8 bk = *(const short8*)&ks[(n * 16 + l15) * 64 + (((kk * 4 + quad) ^ (lane & 7)) << 3)];
        s = __builtin_amdgcn_mfma_f32_16x16x32_bf16(aq[kk], bk, s, 0, 0, 0);
      }
      sa[n] = s;
    }

#pragma unroll
    for (int n = 0; n < 4; n++) {
      bool oob = (c0 + n * 16 + l15) >= NTOK;
#pragma unroll
      for (int rg = 0; rg < 4; rg++) {
        float sc = sa[n][rg] * ATT_SCALE;
        sa[n][rg] = oob ? -1e30f : sc;
      }
    }
    float alpha[4];
#pragma unroll
    for (int rg = 0; rg < 4; rg++) {
      float mx = fmaxf(fmaxf(sa[0][rg], sa[1][rg]), fmaxf(sa[2][rg], sa[3][rg]));
#pragma unroll
      for (int o = 1; o < 16; o <<= 1) mx = fmaxf(mx, __shfl_xor(mx, o, 64));
      float nm = fmaxf(mst[rg], mx);
      alpha[rg] = __expf(mst[rg] - nm);
      mst[rg] = nm;
      float rs = 0.f;
#pragma unroll
      for (int n = 0; n < 4; n++) {
        float p = __expf(sa[n][rg] - nm);
        sa[n][rg] = p;
        rs += p;
      }
#pragma unroll
      for (int o = 1; o < 16; o <<= 1) rs += __shfl_xor(rs, o, 64);
      lst[rg] = lst[rg] * alpha[rg] + rs;
    }

#pragma unroll
    for (int n = 0; n < 4; n++)
#pragma unroll
      for (int rg = 0; rg < 4; rg++) {
        int r = quad * 4 + rg;
        int key = n * 16 + l15;
        int row = w * 16 + r;
        ps[row * 64 + ((((key >> 3) ^ (row & 7)) & 7) << 3) + (key & 7)] = f2bf(sa[n][rg]);
      }

    short8 ap[2];
#pragma unroll
    for (int kk = 0; kk < 2; kk++)
      ap[kk] = *(const short8*)&ps[(w * 16 + l15) * 64 + (((kk * 4 + quad) ^ (lane & 7)) << 3)];
#pragma unroll
    for (int n = 0; n < 4; n++) {
      f32x4 o = Oa[n];
#pragma unroll
      for (int rg = 0; rg < 4; rg++) o[rg] *= alpha[rg];
#pragma unroll
      for (int kk = 0; kk < 2; kk++) {
        short8 bv = *(const short8*)&vt[(n * 16 + l15) * 64 + (((kk * 4 + quad) ^ (lane & 7)) << 3)];
        o = __builtin_amdgcn_mfma_f32_16x16x32_bf16(ap[kk], bv, o, 0, 0, 0);
      }
      Oa[n] = o;
    }
  }

#pragma unroll
  for (int n = 0; n < 4; n++)
#pragma unroll
    for (int rg = 0; rg < 4; rg++) {
      int tok = q0 + w * 16 + quad * 4 + rg;
      if (tok < NTOK)
        out[(size_t)(b * NTOK + tok) * DIMM + h * 64 + n * 16 + l15] =
            f2bf(Oa[n][rg] / lst[rg]);
    }
}

// ---------------------------------------------------------------------------
__global__ __launch_bounds__(256) void ln_k(
    const float* __restrict__ X, const float* __restrict__ s,
    const float* __restrict__ b, unsigned short* __restrict__ Y, int nrows)
{
  const int w = threadIdx.x >> 6, lane = threadIdx.x & 63;
  const int row = blockIdx.x * 4 + w;
  if (row >= nrows) return;
  const float* x = X + (size_t)row * DIMM;
  float4 v0 = *(const float4*)(x + lane * 8);
  float4 v1 = *(const float4*)(x + lane * 8 + 4);
  float xv[8] = {v0.x, v0.y, v0.z, v0.w, v1.x, v1.y, v1.z, v1.w};
  float sum = 0.f, sq = 0.f;
#pragma unroll
  for (int i = 0; i < 8; i++) { sum += xv[i]; sq += xv[i] * xv[i]; }
  sum = wsum(sum); sq = wsum(sq);
  const float mean = sum * (1.0f / DIMM);
  const float var  = sq * (1.0f / DIMM) - mean * mean;
  const float r    = rsqrtf(var + LN_EPS);
  alignas(16) unsigned short tmp[8];
#pragma unroll
  for (int i = 0; i < 8; i++) {
    int d = lane * 8 + i;
    tmp[i] = f2bf((xv[i] - mean) * r * s[d] + b[d]);
  }
  *(uint4*)&Y[(size_t)row * DIMM + lane * 8] = *(const uint4*)tmp;
}

// ---------------------------------------------------------------------------
__global__ __launch_bounds__(256) void assemble_k(
    const float* __restrict__ emb, const float* __restrict__ cls,
    const float* __restrict__ pos, float* __restrict__ X)
{
  int idx = blockIdx.x * 256 + threadIdx.x;
  if (idx >= BATCH * NTOK * DIMM) return;
  int d = idx & (DIMM - 1);
  int t = (idx >> 9) % NTOK;
  int b = idx / (NTOK * DIMM);
  float v = (t == 0) ? cls[d] : emb[((size_t)b * NPATCH + (t - 1)) * DIMM + d];
  X[idx] = v + pos[(size_t)t * DIMM + d];
}

__global__ __launch_bounds__(256) void cast_k(
    const float* __restrict__ X, unsigned short* __restrict__ Y, int n4)
{
  int i = blockIdx.x * 256 + threadIdx.x;
  if (i >= n4) return;
  float4 v = ((const float4*)X)[i];
  alignas(8) unsigned short o[4] = {f2bf(v.x), f2bf(v.y), f2bf(v.z), f2bf(v.w)};
  ((uint2*)Y)[i] = *(const uint2*)o;
}

// transpose + cast: W[z][K][N] fp32 -> Wt[z][N][K] bf16. 32x32 LDS tiles.
__global__ __launch_bounds__(256) void tcast_k(
    const float* __restrict__ W, unsigned short* __restrict__ Wt, int K, int N)
{
  __shared__ float t[32][33];
  const size_t off = (size_t)blockIdx.z * K * N;
  W += off; Wt += off;
  int n0 = blockIdx.x * 32, k0 = blockIdx.y * 32;
  int tx = threadIdx.x & 31, ty = threadIdx.x >> 5;
#pragma unroll
  for (int i = 0; i < 4; i++)
    t[ty + 8 * i][tx] = W[(size_t)(k0 + ty + 8 * i) * N + n0 + tx];
  __syncthreads();
#pragma unroll
  for (int i = 0; i < 4; i++) {
    int n = ty + 8 * i;
    Wt[(size_t)(n0 + n) * K + k0 + tx] = f2bf(t[tx][n]);
  }
}

// ---------------------------------------------------------------------------
__global__ __launch_bounds__(256) void head_k(
    const float* __restrict__ X, const float* __restrict__ s,
    const float* __restrict__ bln, const float* __restrict__ W,
    const float* __restrict__ bh, float* __restrict__ out)
{
  const int w = threadIdx.x >> 6, lane = threadIdx.x & 63;
  if (w >= BATCH) return;
  const float* x = X + (size_t)w * NTOK * DIMM;
  float4 v0 = *(const float4*)(x + lane * 8);
  float4 v1 = *(const float4*)(x + lane * 8 + 4);
  float xv[8] = {v0.x, v0.y, v0.z, v0.w, v1.x, v1.y, v1.z, v1.w};
  float sum = 0.f, sq = 0.f;
#pragma unroll
  for (int i = 0; i < 8; i++) { sum += xv[i]; sq += xv[i] * xv[i]; }
  sum = wsum(sum); sq = wsum(sq);
  const float mean = sum * (1.0f / DIMM);
  const float var  = sq * (1.0f / DIMM) - mean * mean;
  const float r    = rsqrtf(var + LN_EPS);
  float l0 = 0.f, l1 = 0.f;
#pragma unroll
  for (int i = 0; i < 8; i++) {
    int d = lane * 8 + i;
    float xn = (xv[i] - mean) * r * s[d] + bln[d];
    l0 = fmaf(xn, W[d * 2 + 0], l0);
    l1 = fmaf(xn, W[d * 2 + 1], l1);
  }
  l0 = wsum(l0); l1 = wsum(l1);
  if (lane == 0) {
    out[w * 2 + 0] = 1.0f / (1.0f + expf(-(l0 + bh[0])));
    out[w * 2 + 1] = 1.0f / (1.0f + expf(-(l1 + bh[1])));
  }
}

// ---------------------------------------------------------------------------
extern "C" void kernel_launch(void* const* d_in, const int* in_sizes, int n_in,
                              void* d_out, int out_size, void* d_ws, size_t ws_size,
                              hipStream_t stream)
{
  const float* img       = (const float*)d_in[0];
  const float* embed_w   = (const float*)d_in[1];
  const float* embed_b   = (const float*)d_in[2];
  const float* pos_emb   = (const float*)d_in[3];
  const float* cls_token = (const float*)d_in[4];
  const float* ln1_s     = (const float*)d_in[5];
  const float* ln1_b     = (const float*)d_in[6];
  const float* qkv_w     = (const float*)d_in[7];
  const float* out_w     = (const float*)d_in[8];
  const float* out_b     = (const float*)d_in[9];
  const float* ln2_s     = (const float*)d_in[10];
  const float* ln2_b     = (const float*)d_in[11];
  const float* ff_w1     = (const float*)d_in[12];
  const float* ff_b1     = (const float*)d_in[13];
  const float* ff_w2     = (const float*)d_in[14];
  const float* ff_b2     = (const float*)d_in[15];
  const float* head_ln_s = (const float*)d_in[16];
  const float* head_ln_b = (const float*)d_in[17];
  const float* head_w    = (const float*)d_in[18];
  const float* head_b    = (const float*)d_in[19];
  float* out = (float*)d_out;

  char* p = (char*)d_ws;
  auto alloc = [&](size_t bytes) { char* r = p; p += (bytes + 255) & ~(size_t)255; return r; };

  unsigned short* wt_embed = (unsigned short*)alloc((size_t)512 * 512 * 2);
  unsigned short* wt_qkv   = (unsigned short*)alloc((size_t)8 * 1536 * 512 * 2);
  unsigned short* wt_out   = (unsigned short*)alloc((size_t)8 * 512 * 512 * 2);
  unsigned short* wt_ff1   = (unsigned short*)alloc((size_t)8 * 2048 * 512 * 2);
  unsigned short* wt_ff2   = (unsigned short*)alloc((size_t)8 * 512 * 2048 * 2);
  unsigned short* img_bf   = (unsigned short*)alloc((size_t)4096 * 512 * 2);
  float*          x        = (float*)alloc((size_t)ROWS * DIMM * 4);
  unsigned short* h        = (unsigned short*)alloc((size_t)ROWS * DIMM * 2);
  char*           big      = alloc((size_t)ROWS * MLPD * 2);
  unsigned short* qkvb     = (unsigned short*)big;
  unsigned short* attn_out = (unsigned short*)(big + (size_t)ROWS * 1536 * 2);
  unsigned short* ffh      = (unsigned short*)big;
  float*          embuf    = (float*)big;

  dim3 blk(256);

  cast_k<<<(4096 * 512 / 4 + 255) / 256, blk, 0, stream>>>(img, img_bf, 4096 * 512 / 4);
  tcast_k<<<dim3(16, 16, 1), blk, 0, stream>>>(embed_w, wt_embed, 512, 512);
  tcast_k<<<dim3(48, 16, 8), blk, 0, stream>>>(qkv_w, wt_qkv, 512, 1536);
  tcast_k<<<dim3(16, 16, 8), blk, 0, stream>>>(out_w, wt_out, 512, 512);
  tcast_k<<<dim3(64, 16, 8), blk, 0, stream>>>(ff_w1, wt_ff1, 512, 2048);
  tcast_k<<<dim3(16, 64, 8), blk, 0, stream>>>(ff_w2, wt_ff2, 2048, 512);

  // patch embed (M=4096,N=512): 64x64 tiles -> 512 blocks
  mgemm_k<64, 64, 2, 2><<<dim3(8, 64), blk, 0, stream>>>(
      img_bf, wt_embed, embed_b, nullptr, embuf, 4096, 512, 512, 0);
  assemble_k<<<(BATCH * NTOK * DIMM + 255) / 256, blk, 0, stream>>>(
      embuf, cls_token, pos_emb, x);

  const int mt64  = (ROWS + 63) / 64;    // 65
  const int mt128 = (ROWS + 127) / 128;  // 33
  for (int l = 0; l < 8; l++) {
    ln_k<<<(ROWS + 3) / 4, blk, 0, stream>>>(
        x, ln1_s + l * DIMM, ln1_b + l * DIMM, h, ROWS);
    // qkv (N=1536): 64x128 tiles -> 780 blocks
    mgemm_k<64, 128, 1, 4><<<dim3(12, mt64), blk, 0, stream>>>(
        h, wt_qkv + (size_t)l * 1536 * 512, nullptr, nullptr,
        qkvb, ROWS, 1536, 512, 2);
    attn_k<<<dim3((NTOK + 63) / 64, BATCH * NHEADS), blk, 0, stream>>>(
        qkvb, attn_out);
    // proj (N=512): 64x64 tiles -> 520 blocks
    mgemm_k<64, 64, 2, 2><<<dim3(8, mt64), blk, 0, stream>>>(
        attn_out, wt_out + (size_t)l * 512 * 512, out_b + l * DIMM, x,
        x, ROWS, 512, 512, 0);
    ln_k<<<(ROWS + 3) / 4, blk, 0, stream>>>(
        x, ln2_s + l * DIMM, ln2_b + l * DIMM, h, ROWS);
    // ff1 (N=2048): 128x128 tiles -> 528 blocks (best MFMA:ds_read ratio)
    mgemm_k<128, 128, 2, 2><<<dim3(16, mt128), blk, 0, stream>>>(
        h, wt_ff1 + (size_t)l * 2048 * 512, ff_b1 + l * MLPD, nullptr,
        ffh, ROWS, 2048, 512, 1 | 2);
    // ff2 (N=512, K=2048): 64x64 tiles -> 520 blocks
    mgemm_k<64, 64, 2, 2><<<dim3(8, mt64), blk, 0, stream>>>(
        ffh, wt_ff2 + (size_t)l * 512 * 2048, ff_b2 + l * DIMM, x,
        x, ROWS, 512, 2048, 0);
  }

  head_k<<<1, blk, 0, stream>>>(x, head_ln_s, head_ln_b, head_w, head_b, out);
}

// Round 5
// 1398.733 us; speedup vs baseline: 11.4273x; 1.1320x over previous
//
#include <hip/hip_runtime.h>
#include <math.h>
#include <stdint.h>

#define NHEADS   8
#define DHEAD    64
#define DIMM     512
#define MLPD     2048
#define NPATCH   1024
#define NTOK     1025
#define BATCH    4
#define ROWS     (BATCH*NTOK)   /* 4100 */
#define TOKPAD   1088           /* 17*64, vT padded token stride */
#define ATT_SCALE 0.125f
#define LN_EPS   1e-5f

typedef __attribute__((ext_vector_type(8))) short short8;
typedef __attribute__((ext_vector_type(4))) float f32x4;

__device__ __forceinline__ unsigned short f2bf(float f) {
  union { float f; unsigned u; } c; c.f = f;
  unsigned u = c.u;
  return (unsigned short)((u + 0x7fffu + ((u >> 16) & 1u)) >> 16);
}

__device__ __forceinline__ float wsum(float v) {
#pragma unroll
  for (int o = 32; o > 0; o >>= 1) v += __shfl_xor(v, o, 64);
  return v;
}

// async 16B/lane global->LDS. lds base must be wave-uniform; dest = base+lane*16.
__device__ __forceinline__ void gl_lds16(const void* g, const void* l) {
  __builtin_amdgcn_global_load_lds(
      (const __attribute__((address_space(1))) unsigned int*)(uintptr_t)g,
      (__attribute__((address_space(3))) unsigned int*)(unsigned int)(uintptr_t)l,
      16, 0, 0);
}

// ---------------------------------------------------------------------------
// bf16 MFMA GEMM: C[M,N] = A[M,K] @ Bt[N,K]^T (+bias)(+gelu)(+res), out f32/bf16
// Tile TM x TN, BK=64, 256 thr = 4 waves (WR x WC); 16x16x32 MFMA.
// Double-buffered LDS, ONE barrier per K-step: next step's DMA is issued
// right after the barrier and flies during this step's MFMAs (latency hidden
// instead of the stage->barrier->vmcnt(0) serialization of the old loop).
// LDS rows of 64 bf16; k-group g of row r at phys slot g^(r&7) (conflict-free).
// flags: bit0 = gelu, bit1 = bf16 output.
// ---------------------------------------------------------------------------
template <int TM, int TN, int WR, int WC>
__global__ __launch_bounds__(256) void mgemm_k(
    const unsigned short* __restrict__ A, const unsigned short* __restrict__ Bt,
    const float* __restrict__ bias, const float* __restrict__ res,
    void* __restrict__ Cout, int M, int N, int K, int flags)
{
  constexpr int AF = TM / WR / 16;
  constexpr int BF = TN / WC / 16;
  constexpr int AG = TM / 32;
  constexpr int BG = TN / 32;
  __shared__ unsigned short sA[2][TM * 64];
  __shared__ unsigned short sB[2][TN * 64];
  const int tid = threadIdx.x;
  const int w = tid >> 6, lane = tid & 63;
  const int quad = lane >> 4, l15 = lane & 15;
  const int m0 = blockIdx.y * TM, n0 = blockIdx.x * TN;
  const int wrow = (w / WC) * (TM / WR);
  const int wcol = (w % WC) * (TN / WC);
  const int lrow = lane >> 3;
  const int lkg = (lane & 7) ^ lrow;

  // precompute per-group row bases
  size_t abase[AG], bbase[BG];
#pragma unroll
  for (int g = 0; g < AG; g++) {
    int grp = w * AG + g;
    int ar = m0 + grp * 8 + lrow; ar = ar < M ? ar : M - 1;
    abase[g] = (size_t)ar * K + lkg * 8;
  }
#pragma unroll
  for (int g = 0; g < BG; g++) {
    int grp = w * BG + g;
    int br = n0 + grp * 8 + lrow;
    bbase[g] = (size_t)br * K + lkg * 8;
  }

  auto stage = [&](int k0, int buf) {
#pragma unroll
    for (int g = 0; g < AG; g++)
      gl_lds16(A + abase[g] + k0, &sA[buf][(w * AG + g) * 512]);
#pragma unroll
    for (int g = 0; g < BG; g++)
      gl_lds16(Bt + bbase[g] + k0, &sB[buf][(w * BG + g) * 512]);
  };

  f32x4 acc[AF][BF];
#pragma unroll
  for (int i = 0; i < AF; i++)
#pragma unroll
    for (int j = 0; j < BF; j++) { f32x4 z = {0.f, 0.f, 0.f, 0.f}; acc[i][j] = z; }

  stage(0, 0);
  const int nsteps = K >> 6;
  for (int step = 0; step < nsteps; step++) {
    const int buf = step & 1;
    __syncthreads();                       // publishes buf (drains own DMA)
    if (step + 1 < nsteps) stage((step + 1) << 6, buf ^ 1);
#pragma unroll
    for (int kk = 0; kk < 2; kk++) {
      short8 af[AF], bfr[BF];
#pragma unroll
      for (int i = 0; i < AF; i++) {
        int r = wrow + i * 16 + l15;
        af[i] = *(const short8*)&sA[buf][r * 64 + (((kk * 4 + quad) ^ (lane & 7)) << 3)];
      }
#pragma unroll
      for (int j = 0; j < BF; j++) {
        int r = wcol + j * 16 + l15;
        bfr[j] = *(const short8*)&sB[buf][r * 64 + (((kk * 4 + quad) ^ (lane & 7)) << 3)];
      }
#pragma unroll
      for (int i = 0; i < AF; i++)
#pragma unroll
        for (int j = 0; j < BF; j++)
          acc[i][j] = __builtin_amdgcn_mfma_f32_16x16x32_bf16(af[i], bfr[j], acc[i][j], 0, 0, 0);
    }
  }

  const bool do_gelu = flags & 1;
  const bool out_bf  = flags & 2;
#pragma unroll
  for (int i = 0; i < AF; i++) {
#pragma unroll
    for (int rg = 0; rg < 4; rg++) {
      int row = m0 + wrow + i * 16 + quad * 4 + rg;
      if (row >= M) continue;
#pragma unroll
      for (int j = 0; j < BF; j++) {
        int col = n0 + wcol + j * 16 + l15;
        float v = acc[i][j][rg];
        if (bias) v += bias[col];
        if (do_gelu) v = 0.5f * v * (1.0f + erff(v * 0.70710678118654752f));
        if (res) v += res[(size_t)row * N + col];
        if (out_bf) ((unsigned short*)Cout)[(size_t)row * N + col] = f2bf(v);
        else        ((float*)Cout)[(size_t)row * N + col] = v;
      }
    }
  }
}

// ---------------------------------------------------------------------------
// V transpose: qkv[b,tok,1024+h*64+d] -> vT[bh][d][tokpad].  Done ONCE per
// layer instead of 17x inside attention. Grid (17, 32), 256 thr.
// ---------------------------------------------------------------------------
__global__ __launch_bounds__(256) void vtrans_k(
    const unsigned short* __restrict__ qkv, unsigned short* __restrict__ vT)
{
  __shared__ unsigned short tile[64 * 64];
  const int bh = blockIdx.y, b = bh >> 3, h = bh & 7;
  const int t0 = blockIdx.x * 64;
  const int tid = threadIdx.x;
  // load 64 tok x 64 d, 8 bf16 per thread per iter (coalesced), swizzled store
#pragma unroll
  for (int it = 0; it < 2; ++it) {
    int lin = it * 256 + tid;
    int tok = lin >> 3, dg = lin & 7;
    int gt = t0 + tok; gt = gt < NTOK ? gt : NTOK - 1;  // dup rows; masked in attn
    uint4 v = *(const uint4*)(qkv + (size_t)(b * NTOK + gt) * 1536 + 1024 + h * 64 + dg * 8);
    *(uint4*)&tile[tok * 64 + ((dg ^ (tok & 7)) << 3)] = v;
  }
  __syncthreads();
  // write 64 d x 64 tok: thread owns (d, 8 toks), gather 8 scalars, vec store
  unsigned short* outp = vT + ((size_t)bh * 64) * TOKPAD + t0;
#pragma unroll
  for (int it = 0; it < 2; ++it) {
    int lin = it * 256 + tid;
    int d = lin >> 3, tg = lin & 7;
    alignas(16) unsigned short o[8];
#pragma unroll
    for (int j = 0; j < 8; j++) {
      int tok = tg * 8 + j;
      o[j] = tile[tok * 64 + ((((d >> 3) ^ (tok & 7)) & 7) << 3) + (d & 7)];
    }
    *(uint4*)(outp + (size_t)d * TOKPAD + tg * 8) = *(const uint4*)o;
  }
}

// ---------------------------------------------------------------------------
// MFMA flash attention v2. bf16 qkv [B,NTOK,1536] + pre-transposed vT.
// Block: one (b,h), 64 q-rows, 4 waves. Double-buffered K/V^T staging with
// issue-after-barrier (one barrier per chunk). Row-sum of P via MFMA(P, ones).
// ---------------------------------------------------------------------------
__global__ __launch_bounds__(256) void attn_k(
    const unsigned short* __restrict__ qkv, const unsigned short* __restrict__ vT,
    unsigned short* __restrict__ out)
{
  __shared__ unsigned short qs[64 * 64];
  __shared__ unsigned short ps[64 * 64];
  __shared__ unsigned short ks[2][64 * 64];
  __shared__ unsigned short vs[2][64 * 64];   // V^T chunk: rows=d, cols=key
  const int bh = blockIdx.y, b = bh >> 3, h = bh & 7;
  const int q0 = blockIdx.x * 64;
  const int tid = threadIdx.x, w = tid >> 6, lane = tid & 63;
  const int quad = lane >> 4, l15 = lane & 15;
  const int lrow = lane >> 3, lkg = (lane & 7) ^ lrow;
  const unsigned short* qbase = qkv + (size_t)(b * NTOK) * 1536 + h * 64;
  const unsigned short* kbase = qbase + 512;
  const unsigned short* vtb   = vT + (size_t)bh * 64 * TOKPAD;

  auto stage_kv = [&](int c0, int buf) {
#pragma unroll
    for (int g = 0; g < 2; g++) {
      int grp = w * 2 + g;
      int tok = c0 + grp * 8 + lrow; tok = tok < NTOK ? tok : NTOK - 1;
      gl_lds16(kbase + (size_t)tok * 1536 + lkg * 8, &ks[buf][grp * 512]);
      int d = grp * 8 + lrow;                      // vT rows: c0+lkg*8+8 <= TOKPAD
      gl_lds16(vtb + (size_t)d * TOKPAD + c0 + lkg * 8, &vs[buf][grp * 512]);
    }
  };

  // stage Q + first K/V chunk
#pragma unroll
  for (int g = 0; g < 2; g++) {
    int grp = w * 2 + g;
    int tok = q0 + grp * 8 + lrow; tok = tok < NTOK ? tok : NTOK - 1;
    gl_lds16(qbase + (size_t)tok * 1536 + lkg * 8, &qs[grp * 512]);
  }
  stage_kv(0, 0);

  short8 ones;
#pragma unroll
  for (int i = 0; i < 8; i++) ones[i] = (short)0x3F80;  // bf16 1.0

  f32x4 Oa[4];
#pragma unroll
  for (int n = 0; n < 4; n++) { f32x4 z = {0.f, 0.f, 0.f, 0.f}; Oa[n] = z; }
  float mst[4], lst[4];
#pragma unroll
  for (int r = 0; r < 4; r++) { mst[r] = -1e30f; lst[r] = 0.f; }

  const int nchunks = (NTOK + 63) / 64;   // 17
  for (int c = 0; c < nchunks; c++) {
    const int c0 = c * 64;
    const int buf = c & 1;
    __syncthreads();                       // publish chunk c (drains own DMA)
    if (c + 1 < nchunks) stage_kv(c0 + 64, buf ^ 1);

    // S = Q K^T : 16 q-rows x 64 keys per wave
    short8 aq[2];
#pragma unroll
    for (int kk = 0; kk < 2; kk++)
      aq[kk] = *(const short8*)&qs[(w * 16 + l15) * 64 + (((kk * 4 + quad) ^ (lane & 7)) << 3)];
    f32x4 sa[4];
#pragma unroll
    for (int n = 0; n < 4; n++) {
      f32x4 s = {0.f, 0.f, 0.f, 0.f};
#pragma unroll
      for (int kk = 0; kk < 2; kk++) {
        short8 bk = *(const short8*)&ks[buf][(n * 16 + l15) * 64 + (((kk * 4 + quad) ^ (lane & 7)) << 3)];
        s = __builtin_amdgcn_mfma_f32_16x16x32_bf16(aq[kk], bk, s, 0, 0, 0);
      }
      sa[n] = s;
    }

    // scale + mask (only final chunk has invalid keys; p=0 there)
#pragma unroll
    for (int n = 0; n < 4; n++) {
      bool oob = (c0 + n * 16 + l15) >= NTOK;
#pragma unroll
      for (int rg = 0; rg < 4; rg++) {
        float sc = sa[n][rg] * ATT_SCALE;
        sa[n][rg] = oob ? -1e30f : sc;
      }
    }
    // online max + exp (sum comes from MFMA below)
    float alpha[4];
#pragma unroll
    for (int rg = 0; rg < 4; rg++) {
      float mx = fmaxf(fmaxf(sa[0][rg], sa[1][rg]), fmaxf(sa[2][rg], sa[3][rg]));
#pragma unroll
      for (int o = 1; o < 16; o <<= 1) mx = fmaxf(mx, __shfl_xor(mx, o, 64));
      float nm = fmaxf(mst[rg], mx);
      alpha[rg] = __expf(mst[rg] - nm);
      mst[rg] = nm;
#pragma unroll
      for (int n = 0; n < 4; n++) sa[n][rg] = __expf(sa[n][rg] - nm);
    }

    // P -> LDS (A-operand layout; own-wave region, in-wave dep only)
#pragma unroll
    for (int n = 0; n < 4; n++)
#pragma unroll
      for (int rg = 0; rg < 4; rg++) {
        int row = w * 16 + quad * 4 + rg;
        int key = n * 16 + l15;
        ps[row * 64 + ((((key >> 3) ^ (row & 7)) & 7) << 3) + (key & 7)] = f2bf(sa[n][rg]);
      }

    short8 ap[2];
#pragma unroll
    for (int kk = 0; kk < 2; kk++)
      ap[kk] = *(const short8*)&ps[(w * 16 + l15) * 64 + (((kk * 4 + quad) ^ (lane & 7)) << 3)];

    // row-sum of P via MFMA with ones (replaces 16 shuffles)
    f32x4 lsum = {0.f, 0.f, 0.f, 0.f};
#pragma unroll
    for (int kk = 0; kk < 2; kk++)
      lsum = __builtin_amdgcn_mfma_f32_16x16x32_bf16(ap[kk], ones, lsum, 0, 0, 0);

    // O = O*alpha + P V
#pragma unroll
    for (int n = 0; n < 4; n++) {
      f32x4 o = Oa[n];
#pragma unroll
      for (int rg = 0; rg < 4; rg++) o[rg] *= alpha[rg];
#pragma unroll
      for (int kk = 0; kk < 2; kk++) {
        short8 bv = *(const short8*)&vs[buf][(n * 16 + l15) * 64 + (((kk * 4 + quad) ^ (lane & 7)) << 3)];
        o = __builtin_amdgcn_mfma_f32_16x16x32_bf16(ap[kk], bv, o, 0, 0, 0);
      }
      Oa[n] = o;
    }
#pragma unroll
    for (int rg = 0; rg < 4; rg++) lst[rg] = lst[rg] * alpha[rg] + lsum[rg];
  }

#pragma unroll
  for (int n = 0; n < 4; n++)
#pragma unroll
    for (int rg = 0; rg < 4; rg++) {
      int tok = q0 + w * 16 + quad * 4 + rg;
      if (tok < NTOK)
        out[(size_t)(b * NTOK + tok) * DIMM + h * 64 + n * 16 + l15] =
            f2bf(Oa[n][rg] / lst[rg]);
    }
}

// ---------------------------------------------------------------------------
__global__ __launch_bounds__(256) void ln_k(
    const float* __restrict__ X, const float* __restrict__ s,
    const float* __restrict__ b, unsigned short* __restrict__ Y, int nrows)
{
  const int w = threadIdx.x >> 6, lane = threadIdx.x & 63;
  const int row = blockIdx.x * 4 + w;
  if (row >= nrows) return;
  const float* x = X + (size_t)row * DIMM;
  float4 v0 = *(const float4*)(x + lane * 8);
  float4 v1 = *(const float4*)(x + lane * 8 + 4);
  float xv[8] = {v0.x, v0.y, v0.z, v0.w, v1.x, v1.y, v1.z, v1.w};
  float sum = 0.f, sq = 0.f;
#pragma unroll
  for (int i = 0; i < 8; i++) { sum += xv[i]; sq += xv[i] * xv[i]; }
  sum = wsum(sum); sq = wsum(sq);
  const float mean = sum * (1.0f / DIMM);
  const float var  = sq * (1.0f / DIMM) - mean * mean;
  const float r    = rsqrtf(var + LN_EPS);
  alignas(16) unsigned short tmp[8];
#pragma unroll
  for (int i = 0; i < 8; i++) {
    int d = lane * 8 + i;
    tmp[i] = f2bf((xv[i] - mean) * r * s[d] + b[d]);
  }
  *(uint4*)&Y[(size_t)row * DIMM + lane * 8] = *(const uint4*)tmp;
}

// ---------------------------------------------------------------------------
__global__ __launch_bounds__(256) void assemble_k(
    const float* __restrict__ emb, const float* __restrict__ cls,
    const float* __restrict__ pos, float* __restrict__ X)
{
  int idx = blockIdx.x * 256 + threadIdx.x;
  if (idx >= BATCH * NTOK * DIMM) return;
  int d = idx & (DIMM - 1);
  int t = (idx >> 9) % NTOK;
  int b = idx / (NTOK * DIMM);
  float v = (t == 0) ? cls[d] : emb[((size_t)b * NPATCH + (t - 1)) * DIMM + d];
  X[idx] = v + pos[(size_t)t * DIMM + d];
}

__global__ __launch_bounds__(256) void cast_k(
    const float* __restrict__ X, unsigned short* __restrict__ Y, int n4)
{
  int i = blockIdx.x * 256 + threadIdx.x;
  if (i >= n4) return;
  float4 v = ((const float4*)X)[i];
  alignas(8) unsigned short o[4] = {f2bf(v.x), f2bf(v.y), f2bf(v.z), f2bf(v.w)};
  ((uint2*)Y)[i] = *(const uint2*)o;
}

// transpose + cast: W[z][K][N] fp32 -> Wt[z][N][K] bf16. 32x32 LDS tiles.
__global__ __launch_bounds__(256) void tcast_k(
    const float* __restrict__ W, unsigned short* __restrict__ Wt, int K, int N)
{
  __shared__ float t[32][33];
  const size_t off = (size_t)blockIdx.z * K * N;
  W += off; Wt += off;
  int n0 = blockIdx.x * 32, k0 = blockIdx.y * 32;
  int tx = threadIdx.x & 31, ty = threadIdx.x >> 5;
#pragma unroll
  for (int i = 0; i < 4; i++)
    t[ty + 8 * i][tx] = W[(size_t)(k0 + ty + 8 * i) * N + n0 + tx];
  __syncthreads();
#pragma unroll
  for (int i = 0; i < 4; i++) {
    int n = ty + 8 * i;
    Wt[(size_t)(n0 + n) * K + k0 + tx] = f2bf(t[tx][n]);
  }
}

// ---------------------------------------------------------------------------
__global__ __launch_bounds__(256) void head_k(
    const float* __restrict__ X, const float* __restrict__ s,
    const float* __restrict__ bln, const float* __restrict__ W,
    const float* __restrict__ bh, float* __restrict__ out)
{
  const int w = threadIdx.x >> 6, lane = threadIdx.x & 63;
  if (w >= BATCH) return;
  const float* x = X + (size_t)w * NTOK * DIMM;
  float4 v0 = *(const float4*)(x + lane * 8);
  float4 v1 = *(const float4*)(x + lane * 8 + 4);
  float xv[8] = {v0.x, v0.y, v0.z, v0.w, v1.x, v1.y, v1.z, v1.w};
  float sum = 0.f, sq = 0.f;
#pragma unroll
  for (int i = 0; i < 8; i++) { sum += xv[i]; sq += xv[i] * xv[i]; }
  sum = wsum(sum); sq = wsum(sq);
  const float mean = sum * (1.0f / DIMM);
  const float var  = sq * (1.0f / DIMM) - mean * mean;
  const float r    = rsqrtf(var + LN_EPS);
  float l0 = 0.f, l1 = 0.f;
#pragma unroll
  for (int i = 0; i < 8; i++) {
    int d = lane * 8 + i;
    float xn = (xv[i] - mean) * r * s[d] + bln[d];
    l0 = fmaf(xn, W[d * 2 + 0], l0);
    l1 = fmaf(xn, W[d * 2 + 1], l1);
  }
  l0 = wsum(l0); l1 = wsum(l1);
  if (lane == 0) {
    out[w * 2 + 0] = 1.0f / (1.0f + expf(-(l0 + bh[0])));
    out[w * 2 + 1] = 1.0f / (1.0f + expf(-(l1 + bh[1])));
  }
}

// ---------------------------------------------------------------------------
extern "C" void kernel_launch(void* const* d_in, const int* in_sizes, int n_in,
                              void* d_out, int out_size, void* d_ws, size_t ws_size,
                              hipStream_t stream)
{
  const float* img       = (const float*)d_in[0];
  const float* embed_w   = (const float*)d_in[1];
  const float* embed_b   = (const float*)d_in[2];
  const float* pos_emb   = (const float*)d_in[3];
  const float* cls_token = (const float*)d_in[4];
  const float* ln1_s     = (const float*)d_in[5];
  const float* ln1_b     = (const float*)d_in[6];
  const float* qkv_w     = (const float*)d_in[7];
  const float* out_w     = (const float*)d_in[8];
  const float* out_b     = (const float*)d_in[9];
  const float* ln2_s     = (const float*)d_in[10];
  const float* ln2_b     = (const float*)d_in[11];
  const float* ff_w1     = (const float*)d_in[12];
  const float* ff_b1     = (const float*)d_in[13];
  const float* ff_w2     = (const float*)d_in[14];
  const float* ff_b2     = (const float*)d_in[15];
  const float* head_ln_s = (const float*)d_in[16];
  const float* head_ln_b = (const float*)d_in[17];
  const float* head_w    = (const float*)d_in[18];
  const float* head_b    = (const float*)d_in[19];
  float* out = (float*)d_out;

  char* p = (char*)d_ws;
  auto alloc = [&](size_t bytes) { char* r = p; p += (bytes + 255) & ~(size_t)255; return r; };

  unsigned short* wt_embed = (unsigned short*)alloc((size_t)512 * 512 * 2);
  unsigned short* wt_qkv   = (unsigned short*)alloc((size_t)8 * 1536 * 512 * 2);
  unsigned short* wt_out   = (unsigned short*)alloc((size_t)8 * 512 * 512 * 2);
  unsigned short* wt_ff1   = (unsigned short*)alloc((size_t)8 * 2048 * 512 * 2);
  unsigned short* wt_ff2   = (unsigned short*)alloc((size_t)8 * 512 * 2048 * 2);
  unsigned short* img_bf   = (unsigned short*)alloc((size_t)4096 * 512 * 2);
  float*          x        = (float*)alloc((size_t)ROWS * DIMM * 4);
  unsigned short* h        = (unsigned short*)alloc((size_t)ROWS * DIMM * 2);
  unsigned short* vTb      = (unsigned short*)alloc((size_t)32 * 64 * TOKPAD * 2);
  char*           big      = alloc((size_t)ROWS * MLPD * 2);
  unsigned short* qkvb     = (unsigned short*)big;
  unsigned short* attn_out = (unsigned short*)(big + (size_t)ROWS * 1536 * 2);
  unsigned short* ffh      = (unsigned short*)big;
  float*          embuf    = (float*)big;

  dim3 blk(256);

  cast_k<<<(4096 * 512 / 4 + 255) / 256, blk, 0, stream>>>(img, img_bf, 4096 * 512 / 4);
  tcast_k<<<dim3(16, 16, 1), blk, 0, stream>>>(embed_w, wt_embed, 512, 512);
  tcast_k<<<dim3(48, 16, 8), blk, 0, stream>>>(qkv_w, wt_qkv, 512, 1536);
  tcast_k<<<dim3(16, 16, 8), blk, 0, stream>>>(out_w, wt_out, 512, 512);
  tcast_k<<<dim3(64, 16, 8), blk, 0, stream>>>(ff_w1, wt_ff1, 512, 2048);
  tcast_k<<<dim3(16, 64, 8), blk, 0, stream>>>(ff_w2, wt_ff2, 2048, 512);

  mgemm_k<64, 64, 2, 2><<<dim3(8, 64), blk, 0, stream>>>(
      img_bf, wt_embed, embed_b, nullptr, embuf, 4096, 512, 512, 0);
  assemble_k<<<(BATCH * NTOK * DIMM + 255) / 256, blk, 0, stream>>>(
      embuf, cls_token, pos_emb, x);

  const int mt64 = (ROWS + 63) / 64;    // 65
  for (int l = 0; l < 8; l++) {
    ln_k<<<(ROWS + 3) / 4, blk, 0, stream>>>(
        x, ln1_s + l * DIMM, ln1_b + l * DIMM, h, ROWS);
    mgemm_k<64, 128, 1, 4><<<dim3(12, mt64), blk, 0, stream>>>(
        h, wt_qkv + (size_t)l * 1536 * 512, nullptr, nullptr,
        qkvb, ROWS, 1536, 512, 2);
    vtrans_k<<<dim3(17, 32), blk, 0, stream>>>(qkvb, vTb);
    attn_k<<<dim3(17, 32), blk, 0, stream>>>(qkvb, vTb, attn_out);
    mgemm_k<64, 64, 2, 2><<<dim3(8, mt64), blk, 0, stream>>>(
        attn_out, wt_out + (size_t)l * 512 * 512, out_b + l * DIMM, x,
        x, ROWS, 512, 512, 0);
    ln_k<<<(ROWS + 3) / 4, blk, 0, stream>>>(
        x, ln2_s + l * DIMM, ln2_b + l * DIMM, h, ROWS);
    mgemm_k<64, 128, 1, 4><<<dim3(16, mt64), blk, 0, stream>>>(
        h, wt_ff1 + (size_t)l * 2048 * 512, ff_b1 + l * MLPD, nullptr,
        ffh, ROWS, 2048, 512, 1 | 2);
    mgemm_k<64, 64, 2, 2><<<dim3(8, mt64), blk, 0, stream>>>(
        ffh, wt_ff2 + (size_t)l * 512 * 2048, ff_b2 + l * DIMM, x,
        x, ROWS, 512, 2048, 0);
  }

  head_k<<<1, blk, 0, stream>>>(x, head_ln_s, head_ln_b, head_w, head_b, out);
}